// Round 10
// baseline (326.684 us; speedup 1.0000x reference)
//
#include <hip/hip_runtime.h>
#include <hip/hip_bf16.h>

#define B_   4
#define C_   256
#define N_   4096   // H*W
#define NH_  4
#define HD_  64
#define G_   32
#define CPG_ 8      // C_/G_
#define EPS_ 1e-5f

typedef __bf16 bf16x8 __attribute__((ext_vector_type(8)));
typedef __bf16 bf16x4 __attribute__((ext_vector_type(4)));
typedef float  f32x4  __attribute__((ext_vector_type(4)));
typedef unsigned int u32x4 __attribute__((ext_vector_type(4)));
typedef unsigned int u32x2 __attribute__((ext_vector_type(2)));

#define EXP2F(x) __builtin_amdgcn_exp2f(x)   // v_exp_f32: D = 2^S0

static __device__ __forceinline__ unsigned int packbf(float a, float b) {
    __bf16 x = (__bf16)a, y = (__bf16)b;
    unsigned short ux = __builtin_bit_cast(unsigned short, x);
    unsigned short uy = __builtin_bit_cast(unsigned short, y);
    return (unsigned int)ux | ((unsigned int)uy << 16);
}

// ---------------- W pre-conversion: f32 [m][c] -> bf16 [m][c], all 4 matrices ----
__global__ __launch_bounds__(256) void wconv_kernel(const float* __restrict__ w0,
                                                    const float* __restrict__ w1,
                                                    const float* __restrict__ w2,
                                                    const float* __restrict__ w3,
                                                    __bf16* __restrict__ dst) {
    const float* srcs[4] = {w0, w1, w2, w3};
    const float* s = srcs[blockIdx.y];
    __bf16* d = dst + (size_t)blockIdx.y * C_ * C_;
    const int i = blockIdx.x * 256 + threadIdx.x;        // float4 index, 64 blocks/matrix
    float4 v = ((const float4*)s)[i];
    bf16x4 o;
    o[0] = (__bf16)v.x; o[1] = (__bf16)v.y; o[2] = (__bf16)v.z; o[3] = (__bf16)v.w;
    ((bf16x4*)d)[i] = o;
}

// ---------------- GroupNorm: fp32 [b][c][n] -> normalized bf16 X^T [b][n][c] -----
__global__ __launch_bounds__(256) void gn_kernel(const float* __restrict__ in,
                                                 const float* __restrict__ gw,
                                                 const float* __restrict__ gb,
                                                 __bf16* __restrict__ out) {
    const int b = blockIdx.x / G_;
    const int g = blockIdx.x % G_;
    const int tid = threadIdx.x;
    const size_t base = ((size_t)b * C_ + g * CPG_) * N_;
    const float4* pv = (const float4*)(in + base);
    const int NC = (CPG_ * N_) / 4;

    float s = 0.f, ss = 0.f;
    for (int i = tid; i < NC; i += 256) {
        float4 v = pv[i];
        s  += v.x + v.y + v.z + v.w;
        ss += v.x * v.x + v.y * v.y + v.z * v.z + v.w * v.w;
    }
    #pragma unroll
    for (int m = 32; m >= 1; m >>= 1) { s += __shfl_xor(s, m); ss += __shfl_xor(ss, m); }
    __shared__ float red[8];
    const int w = tid >> 6;
    if ((tid & 63) == 0) { red[w] = s; red[4 + w] = ss; }
    __syncthreads();
    s  = red[0] + red[1] + red[2] + red[3];
    ss = red[4] + red[5] + red[6] + red[7];
    const float mean = s * (1.f / 32768.f);
    const float var  = ss * (1.f / 32768.f) - mean * mean;
    const float rinv = rsqrtf(var + EPS_);

    float sc[CPG_], sh[CPG_];
    #pragma unroll
    for (int j = 0; j < CPG_; j++) {
        const float gm = gw[g * CPG_ + j], bt = gb[g * CPG_ + j];
        sc[j] = rinv * gm;
        sh[j] = bt - mean * rinv * gm;
    }
    __bf16* ob = out + (size_t)b * N_ * C_ + g * CPG_;
    for (int n = tid; n < N_; n += 256) {
        bf16x8 o;
        #pragma unroll
        for (int j = 0; j < CPG_; j++) {
            const float v = in[base + (size_t)j * N_ + n];
            o[j] = (__bf16)(v * sc[j] + sh[j]);
        }
        *(bf16x8*)(ob + (size_t)n * C_) = o;
    }
}

// ---------------- conv1x1 GEMM: W-stationary in LDS ------------------------------
// Tile 64n x 128m x K=256. W slice (64KB bf16) staged ONCE into LDS; all 16
// A-fragments (256B/lane) issued upfront into registers; main loop is pure
// ds_read_b128 + MFMA (no global loads, no barriers). 2x2 wave grid.
__global__ __launch_bounds__(256) void gemm_kernel(const __bf16* __restrict__ Wb,
                                                   const float* __restrict__ bias,
                                                   const __bf16* __restrict__ XT,
                                                   __bf16* __restrict__ OUTb,
                                                   float* __restrict__ OUTf,
                                                   const float* __restrict__ RES,
                                                   int mode, float prescale) {
    const int n0 = blockIdx.x * 64;
    const int m0 = blockIdx.y * 128;
    const int b  = blockIdx.z;
    const int tid = threadIdx.x;
    const int w = tid >> 6, lane = tid & 63, quad = lane >> 4, l16 = lane & 15;
    const int wn = (w >> 1) * 32;        // wave n-offset (0/32)
    const int wm = (w & 1) * 64;         // wave m-offset (0/64)

    __shared__ union {
        __bf16 Wl[128][264];             // W tile [m][k], stride 264 (16B-aligned, bank floor)
        __bf16 T1[64][136];              // mode-1 epilogue transpose (overlays Wl)
    } sm;

    // ---- stage W[m0..m0+128)[0..256) -> LDS (64KB, coalesced 16B/lane) ----
    const __bf16* wsrc = Wb + (size_t)m0 * C_;
    #pragma unroll
    for (int i = 0; i < 16; i++) {
        const int e = i * 256 + tid;     // 16B-unit index, 4096 units
        const int row = e >> 5;          // 32 units per 256-wide row
        const int c8 = (e & 31) * 8;
        *(bf16x8*)(&sm.Wl[row][c8]) = *(const bf16x8*)(wsrc + (size_t)row * C_ + c8);
    }

    // ---- issue ALL A-fragments upfront (latency hides under staging+barrier) ----
    const __bf16* ap0 = XT + ((size_t)b * N_ + n0 + wn + l16) * C_ + quad * 8;
    const __bf16* ap1 = ap0 + (size_t)16 * C_;
    bf16x8 areg[2][8];
    #pragma unroll
    for (int ks = 0; ks < 8; ks++) {
        areg[0][ks] = *(const bf16x8*)(ap0 + ks * 32);
        areg[1][ks] = *(const bf16x8*)(ap1 + ks * 32);
    }

    f32x4 acc[2][4];
    #pragma unroll
    for (int qg = 0; qg < 2; qg++)
        #pragma unroll
        for (int jm = 0; jm < 4; jm++) acc[qg][jm] = (f32x4){0.f, 0.f, 0.f, 0.f};

    __syncthreads();

    // ---- main loop: pure LDS + MFMA ----
    #pragma unroll
    for (int ks = 0; ks < 8; ks++) {
        const int kc = ks * 32;
        #pragma unroll
        for (int jm = 0; jm < 4; jm++) {
            bf16x8 bw = *(const bf16x8*)(&sm.Wl[wm + jm * 16 + l16][kc + quad * 8]);
            acc[0][jm] = __builtin_amdgcn_mfma_f32_16x16x32_bf16(areg[0][ks], bw, acc[0][jm], 0, 0, 0);
            acc[1][jm] = __builtin_amdgcn_mfma_f32_16x16x32_bf16(areg[1][ks], bw, acc[1][jm], 0, 0, 0);
        }
    }

    // ---- epilogues ----
    if (mode == 0) {                              // bf16 [c][n] (V for attention)
        #pragma unroll
        for (int qg = 0; qg < 2; qg++) {
            const int nn = n0 + wn + qg * 16 + quad * 4;
            #pragma unroll
            for (int jm = 0; jm < 4; jm++) {
                const int m = m0 + wm + jm * 16 + l16;
                const float bi = bias[m];
                bf16x4 o;
                #pragma unroll
                for (int r = 0; r < 4; r++) o[r] = (__bf16)(acc[qg][jm][r] + bi);
                *(bf16x4*)(OUTb + (size_t)(b * C_ + m) * N_ + nn) = o;
            }
        }
    } else if (mode == 2) {                       // f32 [c][n] + residual (final)
        #pragma unroll
        for (int qg = 0; qg < 2; qg++) {
            const int nn = n0 + wn + qg * 16 + quad * 4;
            #pragma unroll
            for (int jm = 0; jm < 4; jm++) {
                const int m = m0 + wm + jm * 16 + l16;
                const float bi = bias[m];
                const size_t off = (size_t)(b * C_ + m) * N_ + nn;
                const float4 res = *(const float4*)(RES + off);
                f32x4 v;
                v[0] = acc[qg][jm][0] + bi + res.x;
                v[1] = acc[qg][jm][1] + bi + res.y;
                v[2] = acc[qg][jm][2] + bi + res.z;
                v[3] = acc[qg][jm][3] + bi + res.w;
                *(f32x4*)(OUTf + off) = v;
            }
        }
    } else {                                      // mode 1: bf16 [bh][n][d] (Q/K)
        __syncthreads();                          // all Wl reads done before overlay
        #pragma unroll
        for (int qg = 0; qg < 2; qg++)
            #pragma unroll
            for (int jm = 0; jm < 4; jm++) {
                const int m = m0 + wm + jm * 16 + l16;
                const float bi = bias[m];
                #pragma unroll
                for (int r = 0; r < 4; r++)
                    sm.T1[wn + qg * 16 + quad * 4 + r][wm + jm * 16 + l16] =
                        (__bf16)((acc[qg][jm][r] + bi) * prescale);
            }
        __syncthreads();
        const int h0 = m0 >> 6;                   // first head of this m-slice
        #pragma unroll
        for (int i = 0; i < 4; i++) {
            const int idx = i * 256 + tid;        // 0..1023
            const int row = idx >> 4;             // 0..63
            const int c = (idx & 15) * 8;         // 0..120
            const int hh = h0 + (c >> 6);
            const int d = c & 63;
            *(bf16x8*)(OUTb + ((size_t)(b * NH_ + hh) * N_ + n0 + row) * HD_ + d) =
                *(const bf16x8*)(&sm.T1[row][c]);
        }
    }
}

// ---------------- Flash attention v7: K direct-from-global B-frags ---------------
// K fragments are wave-invariant -> LDS-staging K was 4x redundancy through the
// oversubscribed DS pipe. Load kb[][] straight from global (L1/L2-resident tile,
// 2 bh per XCD); only V stays LDS-staged (double-buffered). Halves DS traffic.
__global__ __launch_bounds__(256, 2) void attn_kernel(const __bf16* __restrict__ qT,  // [16][N][64], scale*log2e folded
                                                      const __bf16* __restrict__ kT,  // [16][N][64]
                                                      const __bf16* __restrict__ V,   // [4][256][N]
                                                      __bf16* __restrict__ O) {       // [4][N][256]
    const int flat = blockIdx.y * 32 + blockIdx.x;
    const int bh = flat & 15;          // XCD = flat%8 = bh%8 -> 2 bh per XCD (L2-resident K/V)
    const int qt = flat >> 4;
    const int q0 = qt * 128;
    const int b = bh >> 2, h = bh & 3;
    const int tid = threadIdx.x;
    const int w = tid >> 6, lane = tid & 63, quad = lane >> 4, l16 = lane & 15;

    __shared__ union SMem {
        __bf16 Vt[2][64][72];           // 18 KB V dbuf
        __bf16 Ot[128][72];             // q-major epilogue tile, 18.4 KB
    } sm;

    const __bf16* qTb = qT + (size_t)bh * N_ * HD_;
    const __bf16* kTb = kT + (size_t)bh * N_ * HD_;
    const __bf16* Vb  = V + ((size_t)b * C_ + h * HD_) * N_;

    bf16x8 qa[2][2];
    #pragma unroll
    for (int qg = 0; qg < 2; qg++)
        #pragma unroll
        for (int kk = 0; kk < 2; kk++)
            qa[qg][kk] = *(const bf16x8*)(qTb + (size_t)(q0 + w * 32 + qg * 16 + l16) * HD_ + kk * 32 + quad * 8);

    f32x4 oacc[2][4];
    #pragma unroll
    for (int qg = 0; qg < 2; qg++)
        #pragma unroll
        for (int j = 0; j < 4; j++) oacc[qg][j] = (f32x4){0.f, 0.f, 0.f, 0.f};
    float lsum[2] = {0.f, 0.f};

    const int srow = tid >> 3;          // 0..31
    const int scol = (tid & 7) * 8;

    // preload V tile 0 into registers
    bf16x8 rv[2];
    #pragma unroll
    for (int i = 0; i < 2; i++)
        rv[i] = *(const bf16x8*)(Vb + (size_t)(srow + i * 32) * N_ + scol);

    for (int it = 0; it < N_ / 64; it++) {
        const int cur = it & 1;
        const int m0c = it * 64;
        const int nm0 = ((it + 1) * 64) & (N_ - 1);   // wraps on last iter (harmless reload)
        // K B-fragments direct from global (L1-hit after first wave; wave-invariant)
        bf16x8 kb[2][4];
        #pragma unroll
        for (int kk = 0; kk < 2; kk++)
            #pragma unroll
            for (int j = 0; j < 4; j++)
                kb[kk][j] = *(const bf16x8*)(kTb + (size_t)(m0c + j * 16 + l16) * HD_ + kk * 32 + quad * 8);
        // staged V regs -> LDS buf[cur]
        #pragma unroll
        for (int i = 0; i < 2; i++)
            *(bf16x8*)(&sm.Vt[cur][srow + i * 32][scol]) = rv[i];
        // prefetch next V tile
        #pragma unroll
        for (int i = 0; i < 2; i++)
            rv[i] = *(const bf16x8*)(Vb + (size_t)(srow + i * 32) * N_ + nm0 + scol);
        __syncthreads();
        bf16x8 vb[2][4];
        #pragma unroll
        for (int kk = 0; kk < 2; kk++)
            #pragma unroll
            for (int j = 0; j < 4; j++)
                vb[kk][j] = *(const bf16x8*)(&sm.Vt[cur][j * 16 + l16][kk * 32 + quad * 8]);
        #pragma unroll
        for (int qg = 0; qg < 2; qg++) {
            f32x4 s[4];
            #pragma unroll
            for (int j = 0; j < 4; j++) s[j] = (f32x4){0.f, 0.f, 0.f, 0.f};
            #pragma unroll
            for (int kk = 0; kk < 2; kk++)
                #pragma unroll
                for (int j = 0; j < 4; j++)
                    s[j] = __builtin_amdgcn_mfma_f32_16x16x32_bf16(kb[kk][j], qa[qg][kk], s[j], 0, 0, 0);
            float p[4][4];
            float ls = 0.f;
            #pragma unroll
            for (int j = 0; j < 4; j++) {
                #pragma unroll
                for (int r = 0; r < 4; r++) p[j][r] = EXP2F(s[j][r]);
                ls += (p[j][0] + p[j][1]) + (p[j][2] + p[j][3]);
            }
            lsum[qg] += ls;
            unsigned int pk0[4], pk1[4];
            #pragma unroll
            for (int j = 0; j < 4; j++) {
                pk0[j] = packbf(p[j][0], p[j][1]);
                pk1[j] = packbf(p[j][2], p[j][3]);
            }
            // P^T -> B-frag via permlane swaps (VALU pipe, zero LDS traffic)
            #pragma unroll
            for (int kk = 0; kk < 2; kk++) {
                u32x2 t0 = __builtin_amdgcn_permlane32_swap(pk0[2 * kk], pk0[2 * kk + 1], false, false);
                u32x2 t1 = __builtin_amdgcn_permlane32_swap(pk1[2 * kk], pk1[2 * kk + 1], false, false);
                u32x2 a0 = __builtin_amdgcn_permlane16_swap(t0[0], t0[1], false, false);
                u32x2 a1 = __builtin_amdgcn_permlane16_swap(t1[0], t1[1], false, false);
                bf16x8 pb = __builtin_bit_cast(bf16x8, (u32x4){a0[0], a1[0], a0[1], a1[1]});
                #pragma unroll
                for (int jd = 0; jd < 4; jd++)
                    oacc[qg][jd] = __builtin_amdgcn_mfma_f32_16x16x32_bf16(vb[kk][jd], pb, oacc[qg][jd], 0, 0, 0);
            }
        }
    }
    // final softmax denominators (cross-quad reduce, once)
    float inv[2];
    #pragma unroll
    for (int qg = 0; qg < 2; qg++) {
        float l = lsum[qg];
        l += __shfl_xor(l, 16);
        l += __shfl_xor(l, 32);
        inv[qg] = 1.f / l;
    }
    __syncthreads();   // all Vt reads done before Ot overwrites the union
    #pragma unroll
    for (int qg = 0; qg < 2; qg++) {
        #pragma unroll
        for (int jd = 0; jd < 4; jd++) {
            bf16x4 o;
            #pragma unroll
            for (int r = 0; r < 4; r++) o[r] = (__bf16)(oacc[qg][jd][r] * inv[qg]);
            *(bf16x4*)(&sm.Ot[w * 32 + qg * 16 + l16][jd * 16 + quad * 4]) = o;
        }
    }
    __syncthreads();
    __bf16* Ob = O + ((size_t)b * N_ + q0) * C_ + h * HD_;
    const int row0 = tid >> 3, chh = (tid & 7) * 8;
    #pragma unroll
    for (int i = 0; i < 4; i++) {
        const int row = row0 + i * 32;
        *(bf16x8*)(Ob + (size_t)row * C_ + chh) = *(const bf16x8*)(&sm.Ot[row][chh]);
    }
}

extern "C" void kernel_launch(void* const* d_in, const int* in_sizes, int n_in,
                              void* d_out, int out_size, void* d_ws, size_t ws_size,
                              hipStream_t stream) {
    const float* x     = (const float*)d_in[0];
    const float* cond  = (const float*)d_in[1];
    const float* gnqw  = (const float*)d_in[2];
    const float* gnqb  = (const float*)d_in[3];
    const float* gnkw  = (const float*)d_in[4];
    const float* gnkb  = (const float*)d_in[5];
    const float* wq    = (const float*)d_in[6];
    const float* bq    = (const float*)d_in[7];
    const float* wk    = (const float*)d_in[8];
    const float* bk    = (const float*)d_in[9];
    const float* wv    = (const float*)d_in[10];
    const float* bv    = (const float*)d_in[11];
    const float* wo    = (const float*)d_in[12];
    const float* bo    = (const float*)d_in[13];
    float* out = (float*)d_out;

    const size_t TEN = (size_t)B_ * C_ * N_;
    __bf16* gnx   = (__bf16*)d_ws;      // [b][n][c]
    __bf16* gnc   = gnx + TEN;          // [b][n][c]
    __bf16* qT    = gnc + TEN;          // [bh][n][d]
    __bf16* kT    = qT  + TEN;          // [bh][n][d]
    __bf16* v     = kT  + TEN;          // [b][c][n]
    __bf16* attno = v   + TEN;          // [b][n][c]
    __bf16* wb    = attno + TEN;        // 4x [256][256] bf16 (q,k,v,o)

    wconv_kernel<<<dim3(64, 4), 256, 0, stream>>>(wq, wk, wv, wo, wb);

    gn_kernel<<<dim3(B_ * G_), 256, 0, stream>>>(x,    gnqw, gnqb, gnx);
    gn_kernel<<<dim3(B_ * G_), 256, 0, stream>>>(cond, gnkw, gnkb, gnc);

    const size_t WSZ = (size_t)C_ * C_;
    dim3 gg(N_ / 64, C_ / 128, B_);
    gemm_kernel<<<gg, 256, 0, stream>>>(wb,           bq, gnx, qT, nullptr, nullptr, 1, 0.125f * 1.44269504088896f);
    gemm_kernel<<<gg, 256, 0, stream>>>(wb + WSZ,     bk, gnc, kT, nullptr, nullptr, 1, 1.0f);
    gemm_kernel<<<gg, 256, 0, stream>>>(wb + 2 * WSZ, bv, gnc, v,  nullptr, nullptr, 0, 1.0f);

    attn_kernel<<<dim3(32, 16), 256, 0, stream>>>(qT, kT, v, attno);

    gemm_kernel<<<gg, 256, 0, stream>>>(wb + 3 * WSZ, bo, attno, nullptr, out, x, 2, 1.0f);
}

// Round 11
// 267.219 us; speedup vs baseline: 1.2225x; 1.2225x over previous
//
#include <hip/hip_runtime.h>
#include <hip/hip_bf16.h>

#define B_   4
#define C_   256
#define N_   4096   // H*W
#define NH_  4
#define HD_  64
#define G_   32
#define CPG_ 8      // C_/G_
#define EPS_ 1e-5f

typedef __bf16 bf16x8 __attribute__((ext_vector_type(8)));
typedef __bf16 bf16x4 __attribute__((ext_vector_type(4)));
typedef float  f32x4  __attribute__((ext_vector_type(4)));
typedef unsigned int u32x4 __attribute__((ext_vector_type(4)));
typedef unsigned int u32x2 __attribute__((ext_vector_type(2)));

#define EXP2F(x) __builtin_amdgcn_exp2f(x)   // v_exp_f32: D = 2^S0

static __device__ __forceinline__ unsigned int packbf(float a, float b) {
    __bf16 x = (__bf16)a, y = (__bf16)b;
    unsigned short ux = __builtin_bit_cast(unsigned short, x);
    unsigned short uy = __builtin_bit_cast(unsigned short, y);
    return (unsigned int)ux | ((unsigned int)uy << 16);
}

// ---------------- W pre-conversion: f32 [m][c] -> bf16 [m][c], all 4 matrices ----
__global__ __launch_bounds__(256) void wconv_kernel(const float* __restrict__ w0,
                                                    const float* __restrict__ w1,
                                                    const float* __restrict__ w2,
                                                    const float* __restrict__ w3,
                                                    __bf16* __restrict__ dst) {
    const float* srcs[4] = {w0, w1, w2, w3};
    const float* s = srcs[blockIdx.y];
    __bf16* d = dst + (size_t)blockIdx.y * C_ * C_;
    const int i = blockIdx.x * 256 + threadIdx.x;        // float4 index, 64 blocks/matrix
    float4 v = ((const float4*)s)[i];
    bf16x4 o;
    o[0] = (__bf16)v.x; o[1] = (__bf16)v.y; o[2] = (__bf16)v.z; o[3] = (__bf16)v.w;
    ((bf16x4*)d)[i] = o;
}

// ---------------- GroupNorm: fp32 [b][c][n] -> normalized bf16 X^T [b][n][c] -----
__global__ __launch_bounds__(256) void gn_kernel(const float* __restrict__ in,
                                                 const float* __restrict__ gw,
                                                 const float* __restrict__ gb,
                                                 __bf16* __restrict__ out) {
    const int b = blockIdx.x / G_;
    const int g = blockIdx.x % G_;
    const int tid = threadIdx.x;
    const size_t base = ((size_t)b * C_ + g * CPG_) * N_;
    const float4* pv = (const float4*)(in + base);
    const int NC = (CPG_ * N_) / 4;

    float s = 0.f, ss = 0.f;
    for (int i = tid; i < NC; i += 256) {
        float4 v = pv[i];
        s  += v.x + v.y + v.z + v.w;
        ss += v.x * v.x + v.y * v.y + v.z * v.z + v.w * v.w;
    }
    #pragma unroll
    for (int m = 32; m >= 1; m >>= 1) { s += __shfl_xor(s, m); ss += __shfl_xor(ss, m); }
    __shared__ float red[8];
    const int w = tid >> 6;
    if ((tid & 63) == 0) { red[w] = s; red[4 + w] = ss; }
    __syncthreads();
    s  = red[0] + red[1] + red[2] + red[3];
    ss = red[4] + red[5] + red[6] + red[7];
    const float mean = s * (1.f / 32768.f);
    const float var  = ss * (1.f / 32768.f) - mean * mean;
    const float rinv = rsqrtf(var + EPS_);

    float sc[CPG_], sh[CPG_];
    #pragma unroll
    for (int j = 0; j < CPG_; j++) {
        const float gm = gw[g * CPG_ + j], bt = gb[g * CPG_ + j];
        sc[j] = rinv * gm;
        sh[j] = bt - mean * rinv * gm;
    }
    __bf16* ob = out + (size_t)b * N_ * C_ + g * CPG_;
    for (int n = tid; n < N_; n += 256) {
        bf16x8 o;
        #pragma unroll
        for (int j = 0; j < CPG_; j++) {
            const float v = in[base + (size_t)j * N_ + n];
            o[j] = (__bf16)(v * sc[j] + sh[j]);
        }
        *(bf16x8*)(ob + (size_t)n * C_) = o;
    }
}

// ---------------- fused QKV GEMM: W-stationary in LDS, 3 outputs in one dispatch -
// blockIdx.y: 0-1 = Q (m-half 0/1), 2-3 = K, 4-5 = V. Same inner loop as the
// W-stationary gemm; wave-uniform select. 1536 blocks -> 6 blocks/CU total,
// staging of later blocks overlaps compute of earlier ones.
__global__ __launch_bounds__(256) void qkv_kernel(const __bf16* __restrict__ Wall,  // 3x [256][256] bf16
                                                  const float* __restrict__ bq,
                                                  const float* __restrict__ bk,
                                                  const float* __restrict__ bv,
                                                  const __bf16* __restrict__ Xq,   // [b][n][c]
                                                  const __bf16* __restrict__ Xkv,  // [b][n][c]
                                                  __bf16* __restrict__ Qo,  // [16][N][64]
                                                  __bf16* __restrict__ Ko,  // [16][N][64]
                                                  __bf16* __restrict__ Vo,  // [4][256][N]
                                                  float qscale) {
    const int n0 = blockIdx.x * 64;
    const int sel = blockIdx.y >> 1;                 // 0=Q 1=K 2=V
    const int m0 = (blockIdx.y & 1) * 128;
    const int b  = blockIdx.z;
    const int tid = threadIdx.x;
    const int w = tid >> 6, lane = tid & 63, quad = lane >> 4, l16 = lane & 15;
    const int wn = (w >> 1) * 32;
    const int wm = (w & 1) * 64;

    const __bf16* Wb   = Wall + (size_t)sel * C_ * C_;
    const __bf16* XT   = (sel == 0) ? Xq : Xkv;
    const float*  bias = (sel == 0) ? bq : ((sel == 1) ? bk : bv);
    const float   psc  = (sel == 0) ? qscale : 1.0f;

    __shared__ union {
        __bf16 Wl[128][264];
        __bf16 T1[64][136];
    } sm;

    const __bf16* wsrc = Wb + (size_t)m0 * C_;
    #pragma unroll
    for (int i = 0; i < 16; i++) {
        const int e = i * 256 + tid;
        const int row = e >> 5;
        const int c8 = (e & 31) * 8;
        *(bf16x8*)(&sm.Wl[row][c8]) = *(const bf16x8*)(wsrc + (size_t)row * C_ + c8);
    }

    const __bf16* ap0 = XT + ((size_t)b * N_ + n0 + wn + l16) * C_ + quad * 8;
    const __bf16* ap1 = ap0 + (size_t)16 * C_;
    bf16x8 areg[2][8];
    #pragma unroll
    for (int ks = 0; ks < 8; ks++) {
        areg[0][ks] = *(const bf16x8*)(ap0 + ks * 32);
        areg[1][ks] = *(const bf16x8*)(ap1 + ks * 32);
    }

    f32x4 acc[2][4];
    #pragma unroll
    for (int qg = 0; qg < 2; qg++)
        #pragma unroll
        for (int jm = 0; jm < 4; jm++) acc[qg][jm] = (f32x4){0.f, 0.f, 0.f, 0.f};

    __syncthreads();

    #pragma unroll
    for (int ks = 0; ks < 8; ks++) {
        const int kc = ks * 32;
        #pragma unroll
        for (int jm = 0; jm < 4; jm++) {
            bf16x8 bw = *(const bf16x8*)(&sm.Wl[wm + jm * 16 + l16][kc + quad * 8]);
            acc[0][jm] = __builtin_amdgcn_mfma_f32_16x16x32_bf16(areg[0][ks], bw, acc[0][jm], 0, 0, 0);
            acc[1][jm] = __builtin_amdgcn_mfma_f32_16x16x32_bf16(areg[1][ks], bw, acc[1][jm], 0, 0, 0);
        }
    }

    if (sel == 2) {                               // V: bf16 [c][n]
        #pragma unroll
        for (int qg = 0; qg < 2; qg++) {
            const int nn = n0 + wn + qg * 16 + quad * 4;
            #pragma unroll
            for (int jm = 0; jm < 4; jm++) {
                const int m = m0 + wm + jm * 16 + l16;
                const float bi = bias[m];
                bf16x4 o;
                #pragma unroll
                for (int r = 0; r < 4; r++) o[r] = (__bf16)(acc[qg][jm][r] + bi);
                *(bf16x4*)(Vo + (size_t)(b * C_ + m) * N_ + nn) = o;
            }
        }
    } else {                                      // Q/K: bf16 [bh][n][d]
        __bf16* OUTb = (sel == 0) ? Qo : Ko;
        __syncthreads();
        #pragma unroll
        for (int qg = 0; qg < 2; qg++)
            #pragma unroll
            for (int jm = 0; jm < 4; jm++) {
                const int m = m0 + wm + jm * 16 + l16;
                const float bi = bias[m];
                #pragma unroll
                for (int r = 0; r < 4; r++)
                    sm.T1[wn + qg * 16 + quad * 4 + r][wm + jm * 16 + l16] =
                        (__bf16)((acc[qg][jm][r] + bi) * psc);
            }
        __syncthreads();
        const int h0 = m0 >> 6;
        #pragma unroll
        for (int i = 0; i < 4; i++) {
            const int idx = i * 256 + tid;
            const int row = idx >> 4;
            const int c = (idx & 15) * 8;
            const int hh = h0 + (c >> 6);
            const int d = c & 63;
            *(bf16x8*)(OUTb + ((size_t)(b * NH_ + hh) * N_ + n0 + row) * HD_ + d) =
                *(const bf16x8*)(&sm.T1[row][c]);
        }
    }
}

// ---------------- final GEMM (Wo + residual): W-stationary in LDS ----------------
__global__ __launch_bounds__(256) void gemm_kernel(const __bf16* __restrict__ Wb,
                                                   const float* __restrict__ bias,
                                                   const __bf16* __restrict__ XT,
                                                   float* __restrict__ OUTf,
                                                   const float* __restrict__ RES) {
    const int n0 = blockIdx.x * 64;
    const int m0 = blockIdx.y * 128;
    const int b  = blockIdx.z;
    const int tid = threadIdx.x;
    const int w = tid >> 6, lane = tid & 63, quad = lane >> 4, l16 = lane & 15;
    const int wn = (w >> 1) * 32;
    const int wm = (w & 1) * 64;

    __shared__ __bf16 Wl[128][264];

    const __bf16* wsrc = Wb + (size_t)m0 * C_;
    #pragma unroll
    for (int i = 0; i < 16; i++) {
        const int e = i * 256 + tid;
        const int row = e >> 5;
        const int c8 = (e & 31) * 8;
        *(bf16x8*)(&Wl[row][c8]) = *(const bf16x8*)(wsrc + (size_t)row * C_ + c8);
    }

    const __bf16* ap0 = XT + ((size_t)b * N_ + n0 + wn + l16) * C_ + quad * 8;
    const __bf16* ap1 = ap0 + (size_t)16 * C_;
    bf16x8 areg[2][8];
    #pragma unroll
    for (int ks = 0; ks < 8; ks++) {
        areg[0][ks] = *(const bf16x8*)(ap0 + ks * 32);
        areg[1][ks] = *(const bf16x8*)(ap1 + ks * 32);
    }

    f32x4 acc[2][4];
    #pragma unroll
    for (int qg = 0; qg < 2; qg++)
        #pragma unroll
        for (int jm = 0; jm < 4; jm++) acc[qg][jm] = (f32x4){0.f, 0.f, 0.f, 0.f};

    __syncthreads();

    #pragma unroll
    for (int ks = 0; ks < 8; ks++) {
        const int kc = ks * 32;
        #pragma unroll
        for (int jm = 0; jm < 4; jm++) {
            bf16x8 bw = *(const bf16x8*)(&Wl[wm + jm * 16 + l16][kc + quad * 8]);
            acc[0][jm] = __builtin_amdgcn_mfma_f32_16x16x32_bf16(areg[0][ks], bw, acc[0][jm], 0, 0, 0);
            acc[1][jm] = __builtin_amdgcn_mfma_f32_16x16x32_bf16(areg[1][ks], bw, acc[1][jm], 0, 0, 0);
        }
    }

    #pragma unroll
    for (int qg = 0; qg < 2; qg++) {
        const int nn = n0 + wn + qg * 16 + quad * 4;
        #pragma unroll
        for (int jm = 0; jm < 4; jm++) {
            const int m = m0 + wm + jm * 16 + l16;
            const float bi = bias[m];
            const size_t off = (size_t)(b * C_ + m) * N_ + nn;
            const float4 res = *(const float4*)(RES + off);
            f32x4 v;
            v[0] = acc[qg][jm][0] + bi + res.x;
            v[1] = acc[qg][jm][1] + bi + res.y;
            v[2] = acc[qg][jm][2] + bi + res.z;
            v[3] = acc[qg][jm][3] + bi + res.w;
            *(f32x4*)(OUTf + off) = v;
        }
    }
}

// ---------------- Flash attention v6 (reverted): permlane P^T, K+V in LDS -------
__global__ __launch_bounds__(256, 2) void attn_kernel(const __bf16* __restrict__ qT,  // [16][N][64], scale*log2e folded
                                                      const __bf16* __restrict__ kT,  // [16][N][64]
                                                      const __bf16* __restrict__ V,   // [4][256][N]
                                                      __bf16* __restrict__ O) {       // [4][N][256]
    const int flat = blockIdx.y * 32 + blockIdx.x;
    const int bh = flat & 15;          // XCD = flat%8 = bh%8 -> 2 bh per XCD (L2-resident K/V)
    const int qt = flat >> 4;
    const int q0 = qt * 128;
    const int b = bh >> 2, h = bh & 3;
    const int tid = threadIdx.x;
    const int w = tid >> 6, lane = tid & 63, quad = lane >> 4, l16 = lane & 15;

    __shared__ union SMem {
        struct { __bf16 K[2][64][72]; __bf16 Vt[2][64][72]; } kv;   // 36 KB dbuf
        __bf16 Ot[128][72];                                         // q-major, 18.4 KB
    } sm;

    const __bf16* qTb = qT + (size_t)bh * N_ * HD_;
    const __bf16* kTb = kT + (size_t)bh * N_ * HD_;
    const __bf16* Vb  = V + ((size_t)b * C_ + h * HD_) * N_;

    bf16x8 qa[2][2];
    #pragma unroll
    for (int qg = 0; qg < 2; qg++)
        #pragma unroll
        for (int kk = 0; kk < 2; kk++)
            qa[qg][kk] = *(const bf16x8*)(qTb + (size_t)(q0 + w * 32 + qg * 16 + l16) * HD_ + kk * 32 + quad * 8);

    f32x4 oacc[2][4];
    #pragma unroll
    for (int qg = 0; qg < 2; qg++)
        #pragma unroll
        for (int j = 0; j < 4; j++) oacc[qg][j] = (f32x4){0.f, 0.f, 0.f, 0.f};
    float lsum[2] = {0.f, 0.f};

    const int srow = tid >> 3;          // 0..31
    const int scol = (tid & 7) * 8;

    bf16x8 rk[2], rv[2];
    #pragma unroll
    for (int i = 0; i < 2; i++) {
        const int row = srow + i * 32;
        rk[i] = *(const bf16x8*)(kTb + (size_t)row * HD_ + scol);
        rv[i] = *(const bf16x8*)(Vb + (size_t)row * N_ + scol);
    }

    for (int it = 0; it < N_ / 64; it++) {
        const int cur = it & 1;
        const int nm0 = ((it + 1) * 64) & (N_ - 1);   // wraps on last iter (harmless reload)
        #pragma unroll
        for (int i = 0; i < 2; i++) {
            const int row = srow + i * 32;
            *(bf16x8*)(&sm.kv.K[cur][row][scol])  = rk[i];
            *(bf16x8*)(&sm.kv.Vt[cur][row][scol]) = rv[i];
        }
        #pragma unroll
        for (int i = 0; i < 2; i++) {
            const int row = srow + i * 32;
            rk[i] = *(const bf16x8*)(kTb + (size_t)(nm0 + row) * HD_ + scol);
            rv[i] = *(const bf16x8*)(Vb + (size_t)row * N_ + nm0 + scol);
        }
        __syncthreads();
        bf16x8 kb[2][4], vb[2][4];
        #pragma unroll
        for (int kk = 0; kk < 2; kk++)
            #pragma unroll
            for (int j = 0; j < 4; j++) {
                kb[kk][j] = *(const bf16x8*)(&sm.kv.K[cur][j * 16 + l16][kk * 32 + quad * 8]);
                vb[kk][j] = *(const bf16x8*)(&sm.kv.Vt[cur][j * 16 + l16][kk * 32 + quad * 8]);
            }
        #pragma unroll
        for (int qg = 0; qg < 2; qg++) {
            f32x4 s[4];
            #pragma unroll
            for (int j = 0; j < 4; j++) s[j] = (f32x4){0.f, 0.f, 0.f, 0.f};
            #pragma unroll
            for (int kk = 0; kk < 2; kk++)
                #pragma unroll
                for (int j = 0; j < 4; j++)
                    s[j] = __builtin_amdgcn_mfma_f32_16x16x32_bf16(kb[kk][j], qa[qg][kk], s[j], 0, 0, 0);
            float p[4][4];
            float ls = 0.f;
            #pragma unroll
            for (int j = 0; j < 4; j++) {
                #pragma unroll
                for (int r = 0; r < 4; r++) p[j][r] = EXP2F(s[j][r]);
                ls += (p[j][0] + p[j][1]) + (p[j][2] + p[j][3]);
            }
            lsum[qg] += ls;
            unsigned int pk0[4], pk1[4];
            #pragma unroll
            for (int j = 0; j < 4; j++) {
                pk0[j] = packbf(p[j][0], p[j][1]);
                pk1[j] = packbf(p[j][2], p[j][3]);
            }
            #pragma unroll
            for (int kk = 0; kk < 2; kk++) {
                u32x2 t0 = __builtin_amdgcn_permlane32_swap(pk0[2 * kk], pk0[2 * kk + 1], false, false);
                u32x2 t1 = __builtin_amdgcn_permlane32_swap(pk1[2 * kk], pk1[2 * kk + 1], false, false);
                u32x2 a0 = __builtin_amdgcn_permlane16_swap(t0[0], t0[1], false, false);
                u32x2 a1 = __builtin_amdgcn_permlane16_swap(t1[0], t1[1], false, false);
                bf16x8 pb = __builtin_bit_cast(bf16x8, (u32x4){a0[0], a1[0], a0[1], a1[1]});
                #pragma unroll
                for (int jd = 0; jd < 4; jd++)
                    oacc[qg][jd] = __builtin_amdgcn_mfma_f32_16x16x32_bf16(vb[kk][jd], pb, oacc[qg][jd], 0, 0, 0);
            }
        }
    }
    float inv[2];
    #pragma unroll
    for (int qg = 0; qg < 2; qg++) {
        float l = lsum[qg];
        l += __shfl_xor(l, 16);
        l += __shfl_xor(l, 32);
        inv[qg] = 1.f / l;
    }
    __syncthreads();
    #pragma unroll
    for (int qg = 0; qg < 2; qg++) {
        #pragma unroll
        for (int jd = 0; jd < 4; jd++) {
            bf16x4 o;
            #pragma unroll
            for (int r = 0; r < 4; r++) o[r] = (__bf16)(oacc[qg][jd][r] * inv[qg]);
            *(bf16x4*)(&sm.Ot[w * 32 + qg * 16 + l16][jd * 16 + quad * 4]) = o;
        }
    }
    __syncthreads();
    __bf16* Ob = O + ((size_t)b * N_ + q0) * C_ + h * HD_;
    const int row0 = tid >> 3, chh = (tid & 7) * 8;
    #pragma unroll
    for (int i = 0; i < 4; i++) {
        const int row = row0 + i * 32;
        *(bf16x8*)(Ob + (size_t)row * C_ + chh) = *(const bf16x8*)(&sm.Ot[row][chh]);
    }
}

extern "C" void kernel_launch(void* const* d_in, const int* in_sizes, int n_in,
                              void* d_out, int out_size, void* d_ws, size_t ws_size,
                              hipStream_t stream) {
    const float* x     = (const float*)d_in[0];
    const float* cond  = (const float*)d_in[1];
    const float* gnqw  = (const float*)d_in[2];
    const float* gnqb  = (const float*)d_in[3];
    const float* gnkw  = (const float*)d_in[4];
    const float* gnkb  = (const float*)d_in[5];
    const float* wq    = (const float*)d_in[6];
    const float* bq    = (const float*)d_in[7];
    const float* wk    = (const float*)d_in[8];
    const float* bk    = (const float*)d_in[9];
    const float* wv    = (const float*)d_in[10];
    const float* bv    = (const float*)d_in[11];
    const float* wo    = (const float*)d_in[12];
    const float* bo    = (const float*)d_in[13];
    float* out = (float*)d_out;

    const size_t TEN = (size_t)B_ * C_ * N_;
    __bf16* gnx   = (__bf16*)d_ws;      // [b][n][c]
    __bf16* gnc   = gnx + TEN;          // [b][n][c]
    __bf16* qT    = gnc + TEN;          // [bh][n][d]
    __bf16* kT    = qT  + TEN;          // [bh][n][d]
    __bf16* v     = kT  + TEN;          // [b][c][n]
    __bf16* attno = v   + TEN;          // [b][n][c]
    __bf16* wb    = attno + TEN;        // 4x [256][256] bf16 (q,k,v,o)

    wconv_kernel<<<dim3(64, 4), 256, 0, stream>>>(wq, wk, wv, wo, wb);

    gn_kernel<<<dim3(B_ * G_), 256, 0, stream>>>(x,    gnqw, gnqb, gnx);
    gn_kernel<<<dim3(B_ * G_), 256, 0, stream>>>(cond, gnkw, gnkb, gnc);

    const size_t WSZ = (size_t)C_ * C_;
    qkv_kernel<<<dim3(N_ / 64, 6, B_), 256, 0, stream>>>(wb, bq, bk, bv, gnx, gnc,
                                                         qT, kT, v,
                                                         0.125f * 1.44269504088896f);

    attn_kernel<<<dim3(32, 16), 256, 0, stream>>>(qT, kT, v, attno);

    gemm_kernel<<<dim3(N_ / 64, C_ / 128, B_), 256, 0, stream>>>(wb + 3 * WSZ, bo, attno, out, x);
}

// Round 12
// 251.062 us; speedup vs baseline: 1.3012x; 1.0644x over previous
//
#include <hip/hip_runtime.h>
#include <hip/hip_bf16.h>

#define B_   4
#define C_   256
#define N_   4096   // H*W
#define NH_  4
#define HD_  64
#define G_   32
#define CPG_ 8      // C_/G_
#define EPS_ 1e-5f

typedef __bf16 bf16x8 __attribute__((ext_vector_type(8)));
typedef __bf16 bf16x4 __attribute__((ext_vector_type(4)));
typedef float  f32x4  __attribute__((ext_vector_type(4)));
typedef unsigned int u32x4 __attribute__((ext_vector_type(4)));
typedef unsigned int u32x2 __attribute__((ext_vector_type(2)));

#define EXP2F(x) __builtin_amdgcn_exp2f(x)   // v_exp_f32: D = 2^S0

static __device__ __forceinline__ unsigned int packbf(float a, float b) {
    __bf16 x = (__bf16)a, y = (__bf16)b;
    unsigned short ux = __builtin_bit_cast(unsigned short, x);
    unsigned short uy = __builtin_bit_cast(unsigned short, y);
    return (unsigned int)ux | ((unsigned int)uy << 16);
}

// ---------------- W pre-conversion: f32 [m][c] -> bf16 [m][c], all 4 matrices ----
__global__ __launch_bounds__(256) void wconv_kernel(const float* __restrict__ w0,
                                                    const float* __restrict__ w1,
                                                    const float* __restrict__ w2,
                                                    const float* __restrict__ w3,
                                                    __bf16* __restrict__ dst) {
    const float* srcs[4] = {w0, w1, w2, w3};
    const float* s = srcs[blockIdx.y];
    __bf16* d = dst + (size_t)blockIdx.y * C_ * C_;
    const int i = blockIdx.x * 256 + threadIdx.x;
    float4 v = ((const float4*)s)[i];
    bf16x4 o;
    o[0] = (__bf16)v.x; o[1] = (__bf16)v.y; o[2] = (__bf16)v.z; o[3] = (__bf16)v.w;
    ((bf16x4*)d)[i] = o;
}

// ---------------- GN stats: per (b,g) mean/rinv -> folded sc/sh per channel ------
__global__ __launch_bounds__(256) void gn_stats_kernel(const float* __restrict__ in0,
                                                       const float* __restrict__ in1,
                                                       const float* __restrict__ gw0,
                                                       const float* __restrict__ gb0,
                                                       const float* __restrict__ gw1,
                                                       const float* __restrict__ gb1,
                                                       float* __restrict__ stat) {
    const int which = blockIdx.y;
    const float* in = which ? in1 : in0;
    const float* gw = which ? gw1 : gw0;
    const float* gb = which ? gb1 : gb0;
    const int b = blockIdx.x / G_;
    const int g = blockIdx.x % G_;
    const int tid = threadIdx.x;
    const size_t base = ((size_t)b * C_ + g * CPG_) * N_;
    const float4* pv = (const float4*)(in + base);
    const int NC = (CPG_ * N_) / 4;

    float s = 0.f, ss = 0.f;
    for (int i = tid; i < NC; i += 256) {
        float4 v = pv[i];
        s  += v.x + v.y + v.z + v.w;
        ss += v.x * v.x + v.y * v.y + v.z * v.z + v.w * v.w;
    }
    #pragma unroll
    for (int m = 32; m >= 1; m >>= 1) { s += __shfl_xor(s, m); ss += __shfl_xor(ss, m); }
    __shared__ float red[8];
    const int w = tid >> 6;
    if ((tid & 63) == 0) { red[w] = s; red[4 + w] = ss; }
    __syncthreads();
    s  = red[0] + red[1] + red[2] + red[3];
    ss = red[4] + red[5] + red[6] + red[7];
    const float mean = s * (1.f / 32768.f);
    const float var  = ss * (1.f / 32768.f) - mean * mean;
    const float rinv = rsqrtf(var + EPS_);
    if (tid < CPG_) {
        const int c = g * CPG_ + tid;
        float* sp = stat + (size_t)which * 2 * B_ * C_;
        const float sc = rinv * gw[c];
        sp[b * C_ + c] = sc;
        sp[B_ * C_ + b * C_ + c] = gb[c] - mean * sc;
    }
}

// ---------------- GN normalize+transpose: fp32 [c][n] -> bf16 [n][c], coalesced --
// Block = (n-tile of 64, b, which). Reads rows of in coalesced (lane = n),
// transposes through LDS (16B-chunk XOR swizzle on c by n>>3), writes full
// 512B [n][c] rows coalesced (lane = c-chunk). Kills the 12.5%-efficiency
// 16B/512B-stride scatter of the old GN write.
__global__ __launch_bounds__(256) void gn_norm_kernel(const float* __restrict__ in0,
                                                      const float* __restrict__ in1,
                                                      const float* __restrict__ stat,
                                                      __bf16* __restrict__ out0,
                                                      __bf16* __restrict__ out1) {
    const int which = blockIdx.z;
    const float* in = which ? in1 : in0;
    __bf16* out = which ? out1 : out0;
    const int n0 = blockIdx.x * 64;
    const int b  = blockIdx.y;
    const int tid = threadIdx.x;
    const int w = tid >> 6, lane = tid & 63;
    const float* scp = stat + (size_t)which * 2 * B_ * C_ + b * C_;
    const float* shp = scp + B_ * C_;

    __shared__ __bf16 Lt[64][264];   // [n][c+pad], c stored at chunk (c>>3)^(n>>3)

    #pragma unroll 16
    for (int p = 0; p < 64; p++) {
        const int c = p * 4 + w;                       // wave-uniform channel
        const float v = in[((size_t)(b * C_ + c)) * N_ + n0 + lane];
        const float o = v * scp[c] + shp[c];
        const int ch = (((c >> 3) ^ (lane >> 3)) << 3) + (c & 7);
        Lt[lane][ch] = (__bf16)o;
    }
    __syncthreads();
    #pragma unroll
    for (int q = 0; q < 8; q++) {
        const int r = q * 8 + (tid >> 5);
        const int l = tid & 31;
        const int ch = (l ^ (r >> 3)) << 3;
        *(bf16x8*)(out + ((size_t)b * N_ + n0 + r) * C_ + l * 8) =
            *(const bf16x8*)(&Lt[r][ch]);
    }
}

// ---------------- fused QKV GEMM: W-stationary in LDS ----------------------------
// blockIdx.y: 0-1 = Q (m-half 0/1), 2-3 = K, 4-5 = V. V epilogue now transposes
// through LDS so global stores are 128B-contiguous per m-row (was 8B at 8KB
// stride per lane).
__global__ __launch_bounds__(256) void qkv_kernel(const __bf16* __restrict__ Wall,
                                                  const float* __restrict__ bq,
                                                  const float* __restrict__ bk,
                                                  const float* __restrict__ bv,
                                                  const __bf16* __restrict__ Xq,   // [b][n][c]
                                                  const __bf16* __restrict__ Xkv,  // [b][n][c]
                                                  __bf16* __restrict__ Qo,  // [16][N][64]
                                                  __bf16* __restrict__ Ko,  // [16][N][64]
                                                  __bf16* __restrict__ Vo,  // [4][256][N]
                                                  float qscale) {
    const int n0 = blockIdx.x * 64;
    const int sel = blockIdx.y >> 1;                 // 0=Q 1=K 2=V
    const int m0 = (blockIdx.y & 1) * 128;
    const int b  = blockIdx.z;
    const int tid = threadIdx.x;
    const int w = tid >> 6, lane = tid & 63, quad = lane >> 4, l16 = lane & 15;
    const int wn = (w >> 1) * 32;
    const int wm = (w & 1) * 64;

    const __bf16* Wb   = Wall + (size_t)sel * C_ * C_;
    const __bf16* XT   = (sel == 0) ? Xq : Xkv;
    const float*  bias = (sel == 0) ? bq : ((sel == 1) ? bk : bv);
    const float   psc  = (sel == 0) ? qscale : 1.0f;

    __shared__ union {
        __bf16 Wl[128][264];
        __bf16 T1[64][136];
        __bf16 Tv[128][72];
    } sm;

    const __bf16* wsrc = Wb + (size_t)m0 * C_;
    #pragma unroll
    for (int i = 0; i < 16; i++) {
        const int e = i * 256 + tid;
        const int row = e >> 5;
        const int c8 = (e & 31) * 8;
        *(bf16x8*)(&sm.Wl[row][c8]) = *(const bf16x8*)(wsrc + (size_t)row * C_ + c8);
    }

    const __bf16* ap0 = XT + ((size_t)b * N_ + n0 + wn + l16) * C_ + quad * 8;
    const __bf16* ap1 = ap0 + (size_t)16 * C_;
    bf16x8 areg[2][8];
    #pragma unroll
    for (int ks = 0; ks < 8; ks++) {
        areg[0][ks] = *(const bf16x8*)(ap0 + ks * 32);
        areg[1][ks] = *(const bf16x8*)(ap1 + ks * 32);
    }

    f32x4 acc[2][4];
    #pragma unroll
    for (int qg = 0; qg < 2; qg++)
        #pragma unroll
        for (int jm = 0; jm < 4; jm++) acc[qg][jm] = (f32x4){0.f, 0.f, 0.f, 0.f};

    __syncthreads();

    #pragma unroll
    for (int ks = 0; ks < 8; ks++) {
        const int kc = ks * 32;
        #pragma unroll
        for (int jm = 0; jm < 4; jm++) {
            bf16x8 bw = *(const bf16x8*)(&sm.Wl[wm + jm * 16 + l16][kc + quad * 8]);
            acc[0][jm] = __builtin_amdgcn_mfma_f32_16x16x32_bf16(areg[0][ks], bw, acc[0][jm], 0, 0, 0);
            acc[1][jm] = __builtin_amdgcn_mfma_f32_16x16x32_bf16(areg[1][ks], bw, acc[1][jm], 0, 0, 0);
        }
    }

    if (sel == 2) {                               // V: [c][n] via LDS transpose
        __syncthreads();                          // Wl reads done before overlay
        #pragma unroll
        for (int qg = 0; qg < 2; qg++)
            #pragma unroll
            for (int jm = 0; jm < 4; jm++) {
                const int mm = wm + jm * 16 + l16;
                const int nn = wn + qg * 16 + quad * 4;
                const float bi = bias[m0 + mm];
                bf16x4 o;
                #pragma unroll
                for (int r = 0; r < 4; r++) o[r] = (__bf16)(acc[qg][jm][r] + bi);
                *(bf16x4*)(&sm.Tv[mm][nn]) = o;
            }
        __syncthreads();
        #pragma unroll
        for (int i = 0; i < 4; i++) {
            const int mrow = i * 32 + (tid >> 3);
            const int ch = (tid & 7) * 8;
            *(bf16x8*)(Vo + (size_t)(b * C_ + m0 + mrow) * N_ + n0 + ch) =
                *(const bf16x8*)(&sm.Tv[mrow][ch]);
        }
    } else {                                      // Q/K: bf16 [bh][n][d]
        __bf16* OUTb = (sel == 0) ? Qo : Ko;
        __syncthreads();
        #pragma unroll
        for (int qg = 0; qg < 2; qg++)
            #pragma unroll
            for (int jm = 0; jm < 4; jm++) {
                const int m = m0 + wm + jm * 16 + l16;
                const float bi = bias[m];
                #pragma unroll
                for (int r = 0; r < 4; r++)
                    sm.T1[wn + qg * 16 + quad * 4 + r][wm + jm * 16 + l16] =
                        (__bf16)((acc[qg][jm][r] + bi) * psc);
            }
        __syncthreads();
        const int h0 = m0 >> 6;
        #pragma unroll
        for (int i = 0; i < 4; i++) {
            const int idx = i * 256 + tid;
            const int row = idx >> 4;
            const int c = (idx & 15) * 8;
            const int hh = h0 + (c >> 6);
            const int d = c & 63;
            *(bf16x8*)(OUTb + ((size_t)(b * NH_ + hh) * N_ + n0 + row) * HD_ + d) =
                *(const bf16x8*)(&sm.T1[row][c]);
        }
    }
}

// ---------------- final GEMM (Wo + residual): coalesced epilogue -----------------
// Residual read + f32 store now go through an LDS [m][n] f32 tile -> lane-
// contiguous 256B rows (was 16B/lane at 16KB stride on 32MB of traffic).
__global__ __launch_bounds__(256) void gemm_kernel(const __bf16* __restrict__ Wb,
                                                   const float* __restrict__ bias,
                                                   const __bf16* __restrict__ XT,
                                                   float* __restrict__ OUTf,
                                                   const float* __restrict__ RES) {
    const int n0 = blockIdx.x * 64;
    const int m0 = blockIdx.y * 128;
    const int b  = blockIdx.z;
    const int tid = threadIdx.x;
    const int w = tid >> 6, lane = tid & 63, quad = lane >> 4, l16 = lane & 15;
    const int wn = (w >> 1) * 32;
    const int wm = (w & 1) * 64;

    __shared__ union {
        __bf16 Wl[128][264];
        float  Tf[128][68];
    } sm;

    const __bf16* wsrc = Wb + (size_t)m0 * C_;
    #pragma unroll
    for (int i = 0; i < 16; i++) {
        const int e = i * 256 + tid;
        const int row = e >> 5;
        const int c8 = (e & 31) * 8;
        *(bf16x8*)(&sm.Wl[row][c8]) = *(const bf16x8*)(wsrc + (size_t)row * C_ + c8);
    }

    const __bf16* ap0 = XT + ((size_t)b * N_ + n0 + wn + l16) * C_ + quad * 8;
    const __bf16* ap1 = ap0 + (size_t)16 * C_;
    bf16x8 areg[2][8];
    #pragma unroll
    for (int ks = 0; ks < 8; ks++) {
        areg[0][ks] = *(const bf16x8*)(ap0 + ks * 32);
        areg[1][ks] = *(const bf16x8*)(ap1 + ks * 32);
    }

    f32x4 acc[2][4];
    #pragma unroll
    for (int qg = 0; qg < 2; qg++)
        #pragma unroll
        for (int jm = 0; jm < 4; jm++) acc[qg][jm] = (f32x4){0.f, 0.f, 0.f, 0.f};

    __syncthreads();

    #pragma unroll
    for (int ks = 0; ks < 8; ks++) {
        const int kc = ks * 32;
        #pragma unroll
        for (int jm = 0; jm < 4; jm++) {
            bf16x8 bw = *(const bf16x8*)(&sm.Wl[wm + jm * 16 + l16][kc + quad * 8]);
            acc[0][jm] = __builtin_amdgcn_mfma_f32_16x16x32_bf16(areg[0][ks], bw, acc[0][jm], 0, 0, 0);
            acc[1][jm] = __builtin_amdgcn_mfma_f32_16x16x32_bf16(areg[1][ks], bw, acc[1][jm], 0, 0, 0);
        }
    }

    __syncthreads();                              // Wl reads done before overlay
    #pragma unroll
    for (int qg = 0; qg < 2; qg++)
        #pragma unroll
        for (int jm = 0; jm < 4; jm++) {
            const int mm = wm + jm * 16 + l16;
            const int nn = wn + qg * 16 + quad * 4;
            const float bi = bias[m0 + mm];
            f32x4 o;
            #pragma unroll
            for (int r = 0; r < 4; r++) o[r] = acc[qg][jm][r] + bi;
            *(f32x4*)(&sm.Tf[mm][nn]) = o;
        }
    __syncthreads();
    #pragma unroll
    for (int qp = 0; qp < 8; qp++) {
        const int mrow = qp * 16 + (tid >> 4);
        const int k4 = (tid & 15) * 4;
        const size_t off = (size_t)(b * C_ + m0 + mrow) * N_ + n0 + k4;
        const float4 res = *(const float4*)(RES + off);
        f32x4 v = *(const f32x4*)(&sm.Tf[mrow][k4]);
        v[0] += res.x; v[1] += res.y; v[2] += res.z; v[3] += res.w;
        *(f32x4*)(OUTf + off) = v;
    }
}

// ---------------- Flash attention v6 (unchanged control): permlane P^T ----------
__global__ __launch_bounds__(256, 2) void attn_kernel(const __bf16* __restrict__ qT,  // [16][N][64], scale*log2e folded
                                                      const __bf16* __restrict__ kT,  // [16][N][64]
                                                      const __bf16* __restrict__ V,   // [4][256][N]
                                                      __bf16* __restrict__ O) {       // [4][N][256]
    const int flat = blockIdx.y * 32 + blockIdx.x;
    const int bh = flat & 15;
    const int qt = flat >> 4;
    const int q0 = qt * 128;
    const int b = bh >> 2, h = bh & 3;
    const int tid = threadIdx.x;
    const int w = tid >> 6, lane = tid & 63, quad = lane >> 4, l16 = lane & 15;

    __shared__ union SMem {
        struct { __bf16 K[2][64][72]; __bf16 Vt[2][64][72]; } kv;
        __bf16 Ot[128][72];
    } sm;

    const __bf16* qTb = qT + (size_t)bh * N_ * HD_;
    const __bf16* kTb = kT + (size_t)bh * N_ * HD_;
    const __bf16* Vb  = V + ((size_t)b * C_ + h * HD_) * N_;

    bf16x8 qa[2][2];
    #pragma unroll
    for (int qg = 0; qg < 2; qg++)
        #pragma unroll
        for (int kk = 0; kk < 2; kk++)
            qa[qg][kk] = *(const bf16x8*)(qTb + (size_t)(q0 + w * 32 + qg * 16 + l16) * HD_ + kk * 32 + quad * 8);

    f32x4 oacc[2][4];
    #pragma unroll
    for (int qg = 0; qg < 2; qg++)
        #pragma unroll
        for (int j = 0; j < 4; j++) oacc[qg][j] = (f32x4){0.f, 0.f, 0.f, 0.f};
    float lsum[2] = {0.f, 0.f};

    const int srow = tid >> 3;
    const int scol = (tid & 7) * 8;

    bf16x8 rk[2], rv[2];
    #pragma unroll
    for (int i = 0; i < 2; i++) {
        const int row = srow + i * 32;
        rk[i] = *(const bf16x8*)(kTb + (size_t)row * HD_ + scol);
        rv[i] = *(const bf16x8*)(Vb + (size_t)row * N_ + scol);
    }

    for (int it = 0; it < N_ / 64; it++) {
        const int cur = it & 1;
        const int nm0 = ((it + 1) * 64) & (N_ - 1);
        #pragma unroll
        for (int i = 0; i < 2; i++) {
            const int row = srow + i * 32;
            *(bf16x8*)(&sm.kv.K[cur][row][scol])  = rk[i];
            *(bf16x8*)(&sm.kv.Vt[cur][row][scol]) = rv[i];
        }
        #pragma unroll
        for (int i = 0; i < 2; i++) {
            const int row = srow + i * 32;
            rk[i] = *(const bf16x8*)(kTb + (size_t)(nm0 + row) * HD_ + scol);
            rv[i] = *(const bf16x8*)(Vb + (size_t)row * N_ + nm0 + scol);
        }
        __syncthreads();
        bf16x8 kb[2][4], vb[2][4];
        #pragma unroll
        for (int kk = 0; kk < 2; kk++)
            #pragma unroll
            for (int j = 0; j < 4; j++) {
                kb[kk][j] = *(const bf16x8*)(&sm.kv.K[cur][j * 16 + l16][kk * 32 + quad * 8]);
                vb[kk][j] = *(const bf16x8*)(&sm.kv.Vt[cur][j * 16 + l16][kk * 32 + quad * 8]);
            }
        #pragma unroll
        for (int qg = 0; qg < 2; qg++) {
            f32x4 s[4];
            #pragma unroll
            for (int j = 0; j < 4; j++) s[j] = (f32x4){0.f, 0.f, 0.f, 0.f};
            #pragma unroll
            for (int kk = 0; kk < 2; kk++)
                #pragma unroll
                for (int j = 0; j < 4; j++)
                    s[j] = __builtin_amdgcn_mfma_f32_16x16x32_bf16(kb[kk][j], qa[qg][kk], s[j], 0, 0, 0);
            float p[4][4];
            float ls = 0.f;
            #pragma unroll
            for (int j = 0; j < 4; j++) {
                #pragma unroll
                for (int r = 0; r < 4; r++) p[j][r] = EXP2F(s[j][r]);
                ls += (p[j][0] + p[j][1]) + (p[j][2] + p[j][3]);
            }
            lsum[qg] += ls;
            unsigned int pk0[4], pk1[4];
            #pragma unroll
            for (int j = 0; j < 4; j++) {
                pk0[j] = packbf(p[j][0], p[j][1]);
                pk1[j] = packbf(p[j][2], p[j][3]);
            }
            #pragma unroll
            for (int kk = 0; kk < 2; kk++) {
                u32x2 t0 = __builtin_amdgcn_permlane32_swap(pk0[2 * kk], pk0[2 * kk + 1], false, false);
                u32x2 t1 = __builtin_amdgcn_permlane32_swap(pk1[2 * kk], pk1[2 * kk + 1], false, false);
                u32x2 a0 = __builtin_amdgcn_permlane16_swap(t0[0], t0[1], false, false);
                u32x2 a1 = __builtin_amdgcn_permlane16_swap(t1[0], t1[1], false, false);
                bf16x8 pb = __builtin_bit_cast(bf16x8, (u32x4){a0[0], a1[0], a0[1], a1[1]});
                #pragma unroll
                for (int jd = 0; jd < 4; jd++)
                    oacc[qg][jd] = __builtin_amdgcn_mfma_f32_16x16x32_bf16(vb[kk][jd], pb, oacc[qg][jd], 0, 0, 0);
            }
        }
    }
    float inv[2];
    #pragma unroll
    for (int qg = 0; qg < 2; qg++) {
        float l = lsum[qg];
        l += __shfl_xor(l, 16);
        l += __shfl_xor(l, 32);
        inv[qg] = 1.f / l;
    }
    __syncthreads();
    #pragma unroll
    for (int qg = 0; qg < 2; qg++) {
        #pragma unroll
        for (int jd = 0; jd < 4; jd++) {
            bf16x4 o;
            #pragma unroll
            for (int r = 0; r < 4; r++) o[r] = (__bf16)(oacc[qg][jd][r] * inv[qg]);
            *(bf16x4*)(&sm.Ot[w * 32 + qg * 16 + l16][jd * 16 + quad * 4]) = o;
        }
    }
    __syncthreads();
    __bf16* Ob = O + ((size_t)b * N_ + q0) * C_ + h * HD_;
    const int row0 = tid >> 3, chh = (tid & 7) * 8;
    #pragma unroll
    for (int i = 0; i < 4; i++) {
        const int row = row0 + i * 32;
        *(bf16x8*)(Ob + (size_t)row * C_ + chh) = *(const bf16x8*)(&sm.Ot[row][chh]);
    }
}

extern "C" void kernel_launch(void* const* d_in, const int* in_sizes, int n_in,
                              void* d_out, int out_size, void* d_ws, size_t ws_size,
                              hipStream_t stream) {
    const float* x     = (const float*)d_in[0];
    const float* cond  = (const float*)d_in[1];
    const float* gnqw  = (const float*)d_in[2];
    const float* gnqb  = (const float*)d_in[3];
    const float* gnkw  = (const float*)d_in[4];
    const float* gnkb  = (const float*)d_in[5];
    const float* wq    = (const float*)d_in[6];
    const float* bq    = (const float*)d_in[7];
    const float* wk    = (const float*)d_in[8];
    const float* bk    = (const float*)d_in[9];
    const float* wv    = (const float*)d_in[10];
    const float* bv    = (const float*)d_in[11];
    const float* wo    = (const float*)d_in[12];
    const float* bo    = (const float*)d_in[13];
    float* out = (float*)d_out;

    const size_t TEN = (size_t)B_ * C_ * N_;
    const size_t WSZ = (size_t)C_ * C_;
    __bf16* gnx   = (__bf16*)d_ws;      // [b][n][c]
    __bf16* gnc   = gnx + TEN;          // [b][n][c]
    __bf16* qT    = gnc + TEN;          // [bh][n][d]
    __bf16* kT    = qT  + TEN;          // [bh][n][d]
    __bf16* v     = kT  + TEN;          // [b][c][n]
    __bf16* attno = v   + TEN;          // [b][n][c]
    __bf16* wb    = attno + TEN;        // 4x [256][256] bf16 (q,k,v,o)
    float*  stat  = (float*)(wb + 4 * WSZ);   // [2][2][B][C] f32 (sc/sh per input)

    wconv_kernel<<<dim3(64, 4), 256, 0, stream>>>(wq, wk, wv, wo, wb);

    gn_stats_kernel<<<dim3(B_ * G_, 2), 256, 0, stream>>>(x, cond, gnqw, gnqb, gnkw, gnkb, stat);
    gn_norm_kernel<<<dim3(N_ / 64, B_, 2), 256, 0, stream>>>(x, cond, stat, gnx, gnc);

    qkv_kernel<<<dim3(N_ / 64, 6, B_), 256, 0, stream>>>(wb, bq, bk, bv, gnx, gnc,
                                                         qT, kT, v,
                                                         0.125f * 1.44269504088896f);

    attn_kernel<<<dim3(32, 16), 256, 0, stream>>>(qT, kT, v, attno);

    gemm_kernel<<<dim3(N_ / 64, C_ / 128, B_), 256, 0, stream>>>(wb + 3 * WSZ, bo, attno, out, x);
}

// Round 13
// 250.140 us; speedup vs baseline: 1.3060x; 1.0037x over previous
//
#include <hip/hip_runtime.h>
#include <hip/hip_bf16.h>

#define B_   4
#define C_   256
#define N_   4096   // H*W
#define NH_  4
#define HD_  64
#define G_   32
#define CPG_ 8      // C_/G_
#define EPS_ 1e-5f

typedef __bf16 bf16x8 __attribute__((ext_vector_type(8)));
typedef __bf16 bf16x4 __attribute__((ext_vector_type(4)));
typedef float  f32x4  __attribute__((ext_vector_type(4)));
typedef unsigned int u32x4 __attribute__((ext_vector_type(4)));
typedef unsigned int u32x2 __attribute__((ext_vector_type(2)));

#define EXP2F(x) __builtin_amdgcn_exp2f(x)   // v_exp_f32: D = 2^S0

static __device__ __forceinline__ unsigned int packbf(float a, float b) {
    __bf16 x = (__bf16)a, y = (__bf16)b;
    unsigned short ux = __builtin_bit_cast(unsigned short, x);
    unsigned short uy = __builtin_bit_cast(unsigned short, y);
    return (unsigned int)ux | ((unsigned int)uy << 16);
}

// ---------------- W pre-conversion: f32 [m][c] -> bf16 [m][c], all 4 matrices ----
__global__ __launch_bounds__(256) void wconv_kernel(const float* __restrict__ w0,
                                                    const float* __restrict__ w1,
                                                    const float* __restrict__ w2,
                                                    const float* __restrict__ w3,
                                                    __bf16* __restrict__ dst) {
    const float* srcs[4] = {w0, w1, w2, w3};
    const float* s = srcs[blockIdx.y];
    __bf16* d = dst + (size_t)blockIdx.y * C_ * C_;
    const int i = blockIdx.x * 256 + threadIdx.x;
    float4 v = ((const float4*)s)[i];
    bf16x4 o;
    o[0] = (__bf16)v.x; o[1] = (__bf16)v.y; o[2] = (__bf16)v.z; o[3] = (__bf16)v.w;
    ((bf16x4*)d)[i] = o;
}

// ---------------- GN stats: per (b,g) mean/rinv -> folded sc/sh per channel ------
__global__ __launch_bounds__(256) void gn_stats_kernel(const float* __restrict__ in0,
                                                       const float* __restrict__ in1,
                                                       const float* __restrict__ gw0,
                                                       const float* __restrict__ gb0,
                                                       const float* __restrict__ gw1,
                                                       const float* __restrict__ gb1,
                                                       float* __restrict__ stat) {
    const int which = blockIdx.y;
    const float* in = which ? in1 : in0;
    const float* gw = which ? gw1 : gw0;
    const float* gb = which ? gb1 : gb0;
    const int b = blockIdx.x / G_;
    const int g = blockIdx.x % G_;
    const int tid = threadIdx.x;
    const size_t base = ((size_t)b * C_ + g * CPG_) * N_;
    const float4* pv = (const float4*)(in + base);
    const int NC = (CPG_ * N_) / 4;

    float s = 0.f, ss = 0.f;
    for (int i = tid; i < NC; i += 256) {
        float4 v = pv[i];
        s  += v.x + v.y + v.z + v.w;
        ss += v.x * v.x + v.y * v.y + v.z * v.z + v.w * v.w;
    }
    #pragma unroll
    for (int m = 32; m >= 1; m >>= 1) { s += __shfl_xor(s, m); ss += __shfl_xor(ss, m); }
    __shared__ float red[8];
    const int w = tid >> 6;
    if ((tid & 63) == 0) { red[w] = s; red[4 + w] = ss; }
    __syncthreads();
    s  = red[0] + red[1] + red[2] + red[3];
    ss = red[4] + red[5] + red[6] + red[7];
    const float mean = s * (1.f / 32768.f);
    const float var  = ss * (1.f / 32768.f) - mean * mean;
    const float rinv = rsqrtf(var + EPS_);
    if (tid < CPG_) {
        const int c = g * CPG_ + tid;
        float* sp = stat + (size_t)which * 2 * B_ * C_;
        const float sc = rinv * gw[c];
        sp[b * C_ + c] = sc;
        sp[B_ * C_ + b * C_ + c] = gb[c] - mean * sc;
    }
}

// ---------------- GN normalize+transpose: fp32 [c][n] -> bf16 [n][c], coalesced --
__global__ __launch_bounds__(256) void gn_norm_kernel(const float* __restrict__ in0,
                                                      const float* __restrict__ in1,
                                                      const float* __restrict__ stat,
                                                      __bf16* __restrict__ out0,
                                                      __bf16* __restrict__ out1) {
    const int which = blockIdx.z;
    const float* in = which ? in1 : in0;
    __bf16* out = which ? out1 : out0;
    const int n0 = blockIdx.x * 64;
    const int b  = blockIdx.y;
    const int tid = threadIdx.x;
    const int w = tid >> 6, lane = tid & 63;
    const float* scp = stat + (size_t)which * 2 * B_ * C_ + b * C_;
    const float* shp = scp + B_ * C_;

    __shared__ __bf16 Lt[64][264];   // [n][c+pad], c stored at chunk (c>>3)^(n>>3)

    #pragma unroll 16
    for (int p = 0; p < 64; p++) {
        const int c = p * 4 + w;                       // wave-uniform channel
        const float v = in[((size_t)(b * C_ + c)) * N_ + n0 + lane];
        const float o = v * scp[c] + shp[c];
        const int ch = (((c >> 3) ^ (lane >> 3)) << 3) + (c & 7);
        Lt[lane][ch] = (__bf16)o;
    }
    __syncthreads();
    #pragma unroll
    for (int q = 0; q < 8; q++) {
        const int r = q * 8 + (tid >> 5);
        const int l = tid & 31;
        const int ch = (l ^ (r >> 3)) << 3;
        *(bf16x8*)(out + ((size_t)b * N_ + n0 + r) * C_ + l * 8) =
            *(const bf16x8*)(&Lt[r][ch]);
    }
}

// ---------------- fused QKV GEMM: W-stationary in LDS ----------------------------
__global__ __launch_bounds__(256) void qkv_kernel(const __bf16* __restrict__ Wall,
                                                  const float* __restrict__ bq,
                                                  const float* __restrict__ bk,
                                                  const float* __restrict__ bv,
                                                  const __bf16* __restrict__ Xq,   // [b][n][c]
                                                  const __bf16* __restrict__ Xkv,  // [b][n][c]
                                                  __bf16* __restrict__ Qo,  // [16][N][64]
                                                  __bf16* __restrict__ Ko,  // [16][N][64]
                                                  __bf16* __restrict__ Vo,  // [4][256][N]
                                                  float qscale) {
    const int n0 = blockIdx.x * 64;
    const int sel = blockIdx.y >> 1;                 // 0=Q 1=K 2=V
    const int m0 = (blockIdx.y & 1) * 128;
    const int b  = blockIdx.z;
    const int tid = threadIdx.x;
    const int w = tid >> 6, lane = tid & 63, quad = lane >> 4, l16 = lane & 15;
    const int wn = (w >> 1) * 32;
    const int wm = (w & 1) * 64;

    const __bf16* Wb   = Wall + (size_t)sel * C_ * C_;
    const __bf16* XT   = (sel == 0) ? Xq : Xkv;
    const float*  bias = (sel == 0) ? bq : ((sel == 1) ? bk : bv);
    const float   psc  = (sel == 0) ? qscale : 1.0f;

    __shared__ union {
        __bf16 Wl[128][264];
        __bf16 T1[64][136];
        __bf16 Tv[128][72];
    } sm;

    const __bf16* wsrc = Wb + (size_t)m0 * C_;
    #pragma unroll
    for (int i = 0; i < 16; i++) {
        const int e = i * 256 + tid;
        const int row = e >> 5;
        const int c8 = (e & 31) * 8;
        *(bf16x8*)(&sm.Wl[row][c8]) = *(const bf16x8*)(wsrc + (size_t)row * C_ + c8);
    }

    const __bf16* ap0 = XT + ((size_t)b * N_ + n0 + wn + l16) * C_ + quad * 8;
    const __bf16* ap1 = ap0 + (size_t)16 * C_;
    bf16x8 areg[2][8];
    #pragma unroll
    for (int ks = 0; ks < 8; ks++) {
        areg[0][ks] = *(const bf16x8*)(ap0 + ks * 32);
        areg[1][ks] = *(const bf16x8*)(ap1 + ks * 32);
    }

    f32x4 acc[2][4];
    #pragma unroll
    for (int qg = 0; qg < 2; qg++)
        #pragma unroll
        for (int jm = 0; jm < 4; jm++) acc[qg][jm] = (f32x4){0.f, 0.f, 0.f, 0.f};

    __syncthreads();

    #pragma unroll
    for (int ks = 0; ks < 8; ks++) {
        const int kc = ks * 32;
        #pragma unroll
        for (int jm = 0; jm < 4; jm++) {
            bf16x8 bw = *(const bf16x8*)(&sm.Wl[wm + jm * 16 + l16][kc + quad * 8]);
            acc[0][jm] = __builtin_amdgcn_mfma_f32_16x16x32_bf16(areg[0][ks], bw, acc[0][jm], 0, 0, 0);
            acc[1][jm] = __builtin_amdgcn_mfma_f32_16x16x32_bf16(areg[1][ks], bw, acc[1][jm], 0, 0, 0);
        }
    }

    if (sel == 2) {                               // V: [c][n] via LDS transpose
        __syncthreads();
        #pragma unroll
        for (int qg = 0; qg < 2; qg++)
            #pragma unroll
            for (int jm = 0; jm < 4; jm++) {
                const int mm = wm + jm * 16 + l16;
                const int nn = wn + qg * 16 + quad * 4;
                const float bi = bias[m0 + mm];
                bf16x4 o;
                #pragma unroll
                for (int r = 0; r < 4; r++) o[r] = (__bf16)(acc[qg][jm][r] + bi);
                *(bf16x4*)(&sm.Tv[mm][nn]) = o;
            }
        __syncthreads();
        #pragma unroll
        for (int i = 0; i < 4; i++) {
            const int mrow = i * 32 + (tid >> 3);
            const int ch = (tid & 7) * 8;
            *(bf16x8*)(Vo + (size_t)(b * C_ + m0 + mrow) * N_ + n0 + ch) =
                *(const bf16x8*)(&sm.Tv[mrow][ch]);
        }
    } else {                                      // Q/K: bf16 [bh][n][d]
        __bf16* OUTb = (sel == 0) ? Qo : Ko;
        __syncthreads();
        #pragma unroll
        for (int qg = 0; qg < 2; qg++)
            #pragma unroll
            for (int jm = 0; jm < 4; jm++) {
                const int m = m0 + wm + jm * 16 + l16;
                const float bi = bias[m];
                #pragma unroll
                for (int r = 0; r < 4; r++)
                    sm.T1[wn + qg * 16 + quad * 4 + r][wm + jm * 16 + l16] =
                        (__bf16)((acc[qg][jm][r] + bi) * psc);
            }
        __syncthreads();
        const int h0 = m0 >> 6;
        #pragma unroll
        for (int i = 0; i < 4; i++) {
            const int idx = i * 256 + tid;
            const int row = idx >> 4;
            const int c = (idx & 15) * 8;
            const int hh = h0 + (c >> 6);
            const int d = c & 63;
            *(bf16x8*)(OUTb + ((size_t)(b * NH_ + hh) * N_ + n0 + row) * HD_ + d) =
                *(const bf16x8*)(&sm.T1[row][c]);
        }
    }
}

// ---------------- final GEMM (Wo + residual): coalesced epilogue -----------------
__global__ __launch_bounds__(256) void gemm_kernel(const __bf16* __restrict__ Wb,
                                                   const float* __restrict__ bias,
                                                   const __bf16* __restrict__ XT,
                                                   float* __restrict__ OUTf,
                                                   const float* __restrict__ RES) {
    const int n0 = blockIdx.x * 64;
    const int m0 = blockIdx.y * 128;
    const int b  = blockIdx.z;
    const int tid = threadIdx.x;
    const int w = tid >> 6, lane = tid & 63, quad = lane >> 4, l16 = lane & 15;
    const int wn = (w >> 1) * 32;
    const int wm = (w & 1) * 64;

    __shared__ union {
        __bf16 Wl[128][264];
        float  Tf[128][68];
    } sm;

    const __bf16* wsrc = Wb + (size_t)m0 * C_;
    #pragma unroll
    for (int i = 0; i < 16; i++) {
        const int e = i * 256 + tid;
        const int row = e >> 5;
        const int c8 = (e & 31) * 8;
        *(bf16x8*)(&sm.Wl[row][c8]) = *(const bf16x8*)(wsrc + (size_t)row * C_ + c8);
    }

    const __bf16* ap0 = XT + ((size_t)b * N_ + n0 + wn + l16) * C_ + quad * 8;
    const __bf16* ap1 = ap0 + (size_t)16 * C_;
    bf16x8 areg[2][8];
    #pragma unroll
    for (int ks = 0; ks < 8; ks++) {
        areg[0][ks] = *(const bf16x8*)(ap0 + ks * 32);
        areg[1][ks] = *(const bf16x8*)(ap1 + ks * 32);
    }

    f32x4 acc[2][4];
    #pragma unroll
    for (int qg = 0; qg < 2; qg++)
        #pragma unroll
        for (int jm = 0; jm < 4; jm++) acc[qg][jm] = (f32x4){0.f, 0.f, 0.f, 0.f};

    __syncthreads();

    #pragma unroll
    for (int ks = 0; ks < 8; ks++) {
        const int kc = ks * 32;
        #pragma unroll
        for (int jm = 0; jm < 4; jm++) {
            bf16x8 bw = *(const bf16x8*)(&sm.Wl[wm + jm * 16 + l16][kc + quad * 8]);
            acc[0][jm] = __builtin_amdgcn_mfma_f32_16x16x32_bf16(areg[0][ks], bw, acc[0][jm], 0, 0, 0);
            acc[1][jm] = __builtin_amdgcn_mfma_f32_16x16x32_bf16(areg[1][ks], bw, acc[1][jm], 0, 0, 0);
        }
    }

    __syncthreads();
    #pragma unroll
    for (int qg = 0; qg < 2; qg++)
        #pragma unroll
        for (int jm = 0; jm < 4; jm++) {
            const int mm = wm + jm * 16 + l16;
            const int nn = wn + qg * 16 + quad * 4;
            const float bi = bias[m0 + mm];
            f32x4 o;
            #pragma unroll
            for (int r = 0; r < 4; r++) o[r] = acc[qg][jm][r] + bi;
            *(f32x4*)(&sm.Tf[mm][nn]) = o;
        }
    __syncthreads();
    #pragma unroll
    for (int qp = 0; qp < 8; qp++) {
        const int mrow = qp * 16 + (tid >> 4);
        const int k4 = (tid & 15) * 4;
        const size_t off = (size_t)(b * C_ + m0 + mrow) * N_ + n0 + k4;
        const float4 res = *(const float4*)(RES + off);
        f32x4 v = *(const f32x4*)(&sm.Tf[mrow][k4]);
        v[0] += res.x; v[1] += res.y; v[2] += res.z; v[3] += res.w;
        *(f32x4*)(OUTf + off) = v;
    }
}

// ---------------- Flash attention v8: async barrier (no vmcnt drain in loop) -----
// Same structure as v6 except the main-loop __syncthreads() is replaced by
// lgkmcnt(0)-only wait + raw s_barrier: the next-tile K/V prefetch (issued just
// before the barrier) stays in flight ACROSS the barrier and completes under the
// compute phase, instead of its full L2 latency being exposed at the barrier
// every one of the 64 iterations (hipcc drains vmcnt(0) before __syncthreads).
__global__ __launch_bounds__(256, 2) void attn_kernel(const __bf16* __restrict__ qT,  // [16][N][64], scale*log2e folded
                                                      const __bf16* __restrict__ kT,  // [16][N][64]
                                                      const __bf16* __restrict__ V,   // [4][256][N]
                                                      __bf16* __restrict__ O) {       // [4][N][256]
    const int flat = blockIdx.y * 32 + blockIdx.x;
    const int bh = flat & 15;
    const int qt = flat >> 4;
    const int q0 = qt * 128;
    const int b = bh >> 2, h = bh & 3;
    const int tid = threadIdx.x;
    const int w = tid >> 6, lane = tid & 63, quad = lane >> 4, l16 = lane & 15;

    __shared__ union SMem {
        struct { __bf16 K[2][64][72]; __bf16 Vt[2][64][72]; } kv;
        __bf16 Ot[128][72];
    } sm;

    const __bf16* qTb = qT + (size_t)bh * N_ * HD_;
    const __bf16* kTb = kT + (size_t)bh * N_ * HD_;
    const __bf16* Vb  = V + ((size_t)b * C_ + h * HD_) * N_;

    bf16x8 qa[2][2];
    #pragma unroll
    for (int qg = 0; qg < 2; qg++)
        #pragma unroll
        for (int kk = 0; kk < 2; kk++)
            qa[qg][kk] = *(const bf16x8*)(qTb + (size_t)(q0 + w * 32 + qg * 16 + l16) * HD_ + kk * 32 + quad * 8);

    f32x4 oacc[2][4];
    #pragma unroll
    for (int qg = 0; qg < 2; qg++)
        #pragma unroll
        for (int j = 0; j < 4; j++) oacc[qg][j] = (f32x4){0.f, 0.f, 0.f, 0.f};
    float lsum[2] = {0.f, 0.f};

    const int srow = tid >> 3;
    const int scol = (tid & 7) * 8;

    bf16x8 rk[2], rv[2];
    #pragma unroll
    for (int i = 0; i < 2; i++) {
        const int row = srow + i * 32;
        rk[i] = *(const bf16x8*)(kTb + (size_t)row * HD_ + scol);
        rv[i] = *(const bf16x8*)(Vb + (size_t)row * N_ + scol);
    }

    for (int it = 0; it < N_ / 64; it++) {
        const int cur = it & 1;
        const int nm0 = ((it + 1) * 64) & (N_ - 1);
        // write staged regs -> LDS buf[cur] (compiler inserts vmcnt wait for rk/rv
        // loads here — they were issued a full compute-phase ago, so it's cheap)
        #pragma unroll
        for (int i = 0; i < 2; i++) {
            const int row = srow + i * 32;
            *(bf16x8*)(&sm.kv.K[cur][row][scol])  = rk[i];
            *(bf16x8*)(&sm.kv.Vt[cur][row][scol]) = rv[i];
        }
        // issue next-tile prefetch; these stay in flight across the barrier
        #pragma unroll
        for (int i = 0; i < 2; i++) {
            const int row = srow + i * 32;
            rk[i] = *(const bf16x8*)(kTb + (size_t)(nm0 + row) * HD_ + scol);
            rv[i] = *(const bf16x8*)(Vb + (size_t)row * N_ + nm0 + scol);
        }
        // barrier with DS-only drain (NOT vmcnt) — the T4 counted-wait idea
        asm volatile("s_waitcnt lgkmcnt(0)" ::: "memory");
        __builtin_amdgcn_s_barrier();
        bf16x8 kb[2][4], vb[2][4];
        #pragma unroll
        for (int kk = 0; kk < 2; kk++)
            #pragma unroll
            for (int j = 0; j < 4; j++) {
                kb[kk][j] = *(const bf16x8*)(&sm.kv.K[cur][j * 16 + l16][kk * 32 + quad * 8]);
                vb[kk][j] = *(const bf16x8*)(&sm.kv.Vt[cur][j * 16 + l16][kk * 32 + quad * 8]);
            }
        #pragma unroll
        for (int qg = 0; qg < 2; qg++) {
            f32x4 s[4];
            #pragma unroll
            for (int j = 0; j < 4; j++) s[j] = (f32x4){0.f, 0.f, 0.f, 0.f};
            #pragma unroll
            for (int kk = 0; kk < 2; kk++)
                #pragma unroll
                for (int j = 0; j < 4; j++)
                    s[j] = __builtin_amdgcn_mfma_f32_16x16x32_bf16(kb[kk][j], qa[qg][kk], s[j], 0, 0, 0);
            float p[4][4];
            float ls = 0.f;
            #pragma unroll
            for (int j = 0; j < 4; j++) {
                #pragma unroll
                for (int r = 0; r < 4; r++) p[j][r] = EXP2F(s[j][r]);
                ls += (p[j][0] + p[j][1]) + (p[j][2] + p[j][3]);
            }
            lsum[qg] += ls;
            unsigned int pk0[4], pk1[4];
            #pragma unroll
            for (int j = 0; j < 4; j++) {
                pk0[j] = packbf(p[j][0], p[j][1]);
                pk1[j] = packbf(p[j][2], p[j][3]);
            }
            #pragma unroll
            for (int kk = 0; kk < 2; kk++) {
                u32x2 t0 = __builtin_amdgcn_permlane32_swap(pk0[2 * kk], pk0[2 * kk + 1], false, false);
                u32x2 t1 = __builtin_amdgcn_permlane32_swap(pk1[2 * kk], pk1[2 * kk + 1], false, false);
                u32x2 a0 = __builtin_amdgcn_permlane16_swap(t0[0], t0[1], false, false);
                u32x2 a1 = __builtin_amdgcn_permlane16_swap(t1[0], t1[1], false, false);
                bf16x8 pb = __builtin_bit_cast(bf16x8, (u32x4){a0[0], a1[0], a0[1], a1[1]});
                #pragma unroll
                for (int jd = 0; jd < 4; jd++)
                    oacc[qg][jd] = __builtin_amdgcn_mfma_f32_16x16x32_bf16(vb[kk][jd], pb, oacc[qg][jd], 0, 0, 0);
            }
        }
    }
    float inv[2];
    #pragma unroll
    for (int qg = 0; qg < 2; qg++) {
        float l = lsum[qg];
        l += __shfl_xor(l, 16);
        l += __shfl_xor(l, 32);
        inv[qg] = 1.f / l;
    }
    __syncthreads();
    #pragma unroll
    for (int qg = 0; qg < 2; qg++) {
        #pragma unroll
        for (int jd = 0; jd < 4; jd++) {
            bf16x4 o;
            #pragma unroll
            for (int r = 0; r < 4; r++) o[r] = (__bf16)(oacc[qg][jd][r] * inv[qg]);
            *(bf16x4*)(&sm.Ot[w * 32 + qg * 16 + l16][jd * 16 + quad * 4]) = o;
        }
    }
    __syncthreads();
    __bf16* Ob = O + ((size_t)b * N_ + q0) * C_ + h * HD_;
    const int row0 = tid >> 3, chh = (tid & 7) * 8;
    #pragma unroll
    for (int i = 0; i < 4; i++) {
        const int row = row0 + i * 32;
        *(bf16x8*)(Ob + (size_t)row * C_ + chh) = *(const bf16x8*)(&sm.Ot[row][chh]);
    }
}

extern "C" void kernel_launch(void* const* d_in, const int* in_sizes, int n_in,
                              void* d_out, int out_size, void* d_ws, size_t ws_size,
                              hipStream_t stream) {
    const float* x     = (const float*)d_in[0];
    const float* cond  = (const float*)d_in[1];
    const float* gnqw  = (const float*)d_in[2];
    const float* gnqb  = (const float*)d_in[3];
    const float* gnkw  = (const float*)d_in[4];
    const float* gnkb  = (const float*)d_in[5];
    const float* wq    = (const float*)d_in[6];
    const float* bq    = (const float*)d_in[7];
    const float* wk    = (const float*)d_in[8];
    const float* bk    = (const float*)d_in[9];
    const float* wv    = (const float*)d_in[10];
    const float* bv    = (const float*)d_in[11];
    const float* wo    = (const float*)d_in[12];
    const float* bo    = (const float*)d_in[13];
    float* out = (float*)d_out;

    const size_t TEN = (size_t)B_ * C_ * N_;
    const size_t WSZ = (size_t)C_ * C_;
    __bf16* gnx   = (__bf16*)d_ws;      // [b][n][c]
    __bf16* gnc   = gnx + TEN;          // [b][n][c]
    __bf16* qT    = gnc + TEN;          // [bh][n][d]
    __bf16* kT    = qT  + TEN;          // [bh][n][d]
    __bf16* v     = kT  + TEN;          // [b][c][n]
    __bf16* attno = v   + TEN;          // [b][n][c]
    __bf16* wb    = attno + TEN;        // 4x [256][256] bf16 (q,k,v,o)
    float*  stat  = (float*)(wb + 4 * WSZ);   // [2][2][B][C] f32 (sc/sh per input)

    wconv_kernel<<<dim3(64, 4), 256, 0, stream>>>(wq, wk, wv, wo, wb);

    gn_stats_kernel<<<dim3(B_ * G_, 2), 256, 0, stream>>>(x, cond, gnqw, gnqb, gnkw, gnkb, stat);
    gn_norm_kernel<<<dim3(N_ / 64, B_, 2), 256, 0, stream>>>(x, cond, stat, gnx, gnc);

    qkv_kernel<<<dim3(N_ / 64, 6, B_), 256, 0, stream>>>(wb, bq, bk, bv, gnx, gnc,
                                                         qT, kT, v,
                                                         0.125f * 1.44269504088896f);

    attn_kernel<<<dim3(32, 16), 256, 0, stream>>>(qT, kT, v, attno);

    gemm_kernel<<<dim3(N_ / 64, C_ / 128, B_), 256, 0, stream>>>(wb + 3 * WSZ, bo, attno, out, x);
}

// Round 16
// 237.146 us; speedup vs baseline: 1.3776x; 1.0548x over previous
//
#include <hip/hip_runtime.h>
#include <hip/hip_bf16.h>

#define B_   4
#define C_   256
#define N_   4096   // H*W
#define NH_  4
#define HD_  64
#define G_   32
#define CPG_ 8      // C_/G_
#define EPS_ 1e-5f

typedef __bf16 bf16x8 __attribute__((ext_vector_type(8)));
typedef __bf16 bf16x4 __attribute__((ext_vector_type(4)));
typedef float  f32x4  __attribute__((ext_vector_type(4)));
typedef unsigned int u32x4 __attribute__((ext_vector_type(4)));
typedef unsigned int u32x2 __attribute__((ext_vector_type(2)));

#define EXP2F(x) __builtin_amdgcn_exp2f(x)   // v_exp_f32: D = 2^S0

static __device__ __forceinline__ unsigned int packbf(float a, float b) {
    __bf16 x = (__bf16)a, y = (__bf16)b;
    unsigned short ux = __builtin_bit_cast(unsigned short, x);
    unsigned short uy = __builtin_bit_cast(unsigned short, y);
    return (unsigned int)ux | ((unsigned int)uy << 16);
}

// ---------------- W pre-conversion: f32 [m][c] -> bf16 [m][c], all 4 matrices ----
__global__ __launch_bounds__(256) void wconv_kernel(const float* __restrict__ w0,
                                                    const float* __restrict__ w1,
                                                    const float* __restrict__ w2,
                                                    const float* __restrict__ w3,
                                                    __bf16* __restrict__ dst) {
    const float* srcs[4] = {w0, w1, w2, w3};
    const float* s = srcs[blockIdx.y];
    __bf16* d = dst + (size_t)blockIdx.y * C_ * C_;
    const int i = blockIdx.x * 256 + threadIdx.x;
    float4 v = ((const float4*)s)[i];
    bf16x4 o;
    o[0] = (__bf16)v.x; o[1] = (__bf16)v.y; o[2] = (__bf16)v.z; o[3] = (__bf16)v.w;
    ((bf16x4*)d)[i] = o;
}

// ---------------- GN stats: 1024 threads (4 waves/SIMD of TLP, was 1) -----------
__global__ __launch_bounds__(1024) void gn_stats_kernel(const float* __restrict__ in0,
                                                        const float* __restrict__ in1,
                                                        const float* __restrict__ gw0,
                                                        const float* __restrict__ gb0,
                                                        const float* __restrict__ gw1,
                                                        const float* __restrict__ gb1,
                                                        float* __restrict__ stat) {
    const int which = blockIdx.y;
    const float* in = which ? in1 : in0;
    const float* gw = which ? gw1 : gw0;
    const float* gb = which ? gb1 : gb0;
    const int b = blockIdx.x / G_;
    const int g = blockIdx.x % G_;
    const int tid = threadIdx.x;
    const size_t base = ((size_t)b * C_ + g * CPG_) * N_;
    const float4* pv = (const float4*)(in + base);
    const int NC = (CPG_ * N_) / 4;            // 8192 float4s -> 8 per thread

    float s = 0.f, ss = 0.f;
    #pragma unroll
    for (int i = tid; i < NC; i += 1024) {
        float4 v = pv[i];
        s  += v.x + v.y + v.z + v.w;
        ss += v.x * v.x + v.y * v.y + v.z * v.z + v.w * v.w;
    }
    #pragma unroll
    for (int m = 32; m >= 1; m >>= 1) { s += __shfl_xor(s, m); ss += __shfl_xor(ss, m); }
    __shared__ float red[32];
    const int w = tid >> 6;                    // 0..15
    if ((tid & 63) == 0) { red[w] = s; red[16 + w] = ss; }
    __syncthreads();
    s = 0.f; ss = 0.f;
    #pragma unroll
    for (int i = 0; i < 16; i++) { s += red[i]; ss += red[16 + i]; }
    const float mean = s * (1.f / 32768.f);
    const float var  = ss * (1.f / 32768.f) - mean * mean;
    const float rinv = rsqrtf(var + EPS_);
    if (tid < CPG_) {
        const int c = g * CPG_ + tid;
        float* sp = stat + (size_t)which * 2 * B_ * C_;
        const float sc = rinv * gw[c];
        sp[b * C_ + c] = sc;
        sp[B_ * C_ + b * C_ + c] = gb[c] - mean * sc;
    }
}

// ---------------- GN normalize+transpose: fp32 [c][n] -> bf16 [n][c], coalesced --
// (256,4): LDS 33.8KB -> 4 blocks/CU; declare it so the VGPR budget matches.
__global__ __launch_bounds__(256, 4) void gn_norm_kernel(const float* __restrict__ in0,
                                                         const float* __restrict__ in1,
                                                         const float* __restrict__ stat,
                                                         __bf16* __restrict__ out0,
                                                         __bf16* __restrict__ out1) {
    const int which = blockIdx.z;
    const float* in = which ? in1 : in0;
    __bf16* out = which ? out1 : out0;
    const int n0 = blockIdx.x * 64;
    const int b  = blockIdx.y;
    const int tid = threadIdx.x;
    const int w = tid >> 6, lane = tid & 63;
    const float* scp = stat + (size_t)which * 2 * B_ * C_ + b * C_;
    const float* shp = scp + B_ * C_;

    __shared__ __bf16 Lt[64][264];   // [n][c+pad], c stored at chunk (c>>3)^(n>>3)

    #pragma unroll 16
    for (int p = 0; p < 64; p++) {
        const int c = p * 4 + w;                       // wave-uniform channel
        const float v = in[((size_t)(b * C_ + c)) * N_ + n0 + lane];
        const float o = v * scp[c] + shp[c];
        const int ch = (((c >> 3) ^ (lane >> 3)) << 3) + (c & 7);
        Lt[lane][ch] = (__bf16)o;
    }
    __syncthreads();
    #pragma unroll
    for (int q = 0; q < 8; q++) {
        const int r = q * 8 + (tid >> 5);
        const int l = tid & 31;
        const int ch = (l ^ (r >> 3)) << 3;
        *(bf16x8*)(out + ((size_t)b * N_ + n0 + r) * C_ + l * 8) =
            *(const bf16x8*)(&Lt[r][ch]);
    }
}

// ---------------- fused QKV GEMM: W-stationary in LDS ----------------------------
// (256,2): LDS 67.6KB caps at 2 blocks/CU anyway; declaring it raises the VGPR
// ceiling to 256 so the 16 A-fragment loads + 16 W-staging loads can ALL stay
// in flight (plain launch_bounds let the compiler throttle MLP for occupancy).
__global__ __launch_bounds__(256, 2) void qkv_kernel(const __bf16* __restrict__ Wall,
                                                     const float* __restrict__ bq,
                                                     const float* __restrict__ bk,
                                                     const float* __restrict__ bv,
                                                     const __bf16* __restrict__ Xq,   // [b][n][c]
                                                     const __bf16* __restrict__ Xkv,  // [b][n][c]
                                                     __bf16* __restrict__ Qo,  // [16][N][64]
                                                     __bf16* __restrict__ Ko,  // [16][N][64]
                                                     __bf16* __restrict__ Vo,  // [4][256][N]
                                                     float qscale) {
    const int n0 = blockIdx.x * 64;
    const int sel = blockIdx.y >> 1;                 // 0=Q 1=K 2=V
    const int m0 = (blockIdx.y & 1) * 128;
    const int b  = blockIdx.z;
    const int tid = threadIdx.x;
    const int w = tid >> 6, lane = tid & 63, quad = lane >> 4, l16 = lane & 15;
    const int wn = (w >> 1) * 32;
    const int wm = (w & 1) * 64;

    const __bf16* Wb   = Wall + (size_t)sel * C_ * C_;
    const __bf16* XT   = (sel == 0) ? Xq : Xkv;
    const float*  bias = (sel == 0) ? bq : ((sel == 1) ? bk : bv);
    const float   psc  = (sel == 0) ? qscale : 1.0f;

    __shared__ union {
        __bf16 Wl[128][264];
        __bf16 T1[64][136];
        __bf16 Tv[128][72];
    } sm;

    const __bf16* wsrc = Wb + (size_t)m0 * C_;
    #pragma unroll
    for (int i = 0; i < 16; i++) {
        const int e = i * 256 + tid;
        const int row = e >> 5;
        const int c8 = (e & 31) * 8;
        *(bf16x8*)(&sm.Wl[row][c8]) = *(const bf16x8*)(wsrc + (size_t)row * C_ + c8);
    }

    const __bf16* ap0 = XT + ((size_t)b * N_ + n0 + wn + l16) * C_ + quad * 8;
    const __bf16* ap1 = ap0 + (size_t)16 * C_;
    bf16x8 areg[2][8];
    #pragma unroll
    for (int ks = 0; ks < 8; ks++) {
        areg[0][ks] = *(const bf16x8*)(ap0 + ks * 32);
        areg[1][ks] = *(const bf16x8*)(ap1 + ks * 32);
    }

    f32x4 acc[2][4];
    #pragma unroll
    for (int qg = 0; qg < 2; qg++)
        #pragma unroll
        for (int jm = 0; jm < 4; jm++) acc[qg][jm] = (f32x4){0.f, 0.f, 0.f, 0.f};

    __syncthreads();

    #pragma unroll
    for (int ks = 0; ks < 8; ks++) {
        const int kc = ks * 32;
        #pragma unroll
        for (int jm = 0; jm < 4; jm++) {
            bf16x8 bw = *(const bf16x8*)(&sm.Wl[wm + jm * 16 + l16][kc + quad * 8]);
            acc[0][jm] = __builtin_amdgcn_mfma_f32_16x16x32_bf16(areg[0][ks], bw, acc[0][jm], 0, 0, 0);
            acc[1][jm] = __builtin_amdgcn_mfma_f32_16x16x32_bf16(areg[1][ks], bw, acc[1][jm], 0, 0, 0);
        }
    }

    if (sel == 2) {                               // V: [c][n] via LDS transpose
        __syncthreads();
        #pragma unroll
        for (int qg = 0; qg < 2; qg++)
            #pragma unroll
            for (int jm = 0; jm < 4; jm++) {
                const int mm = wm + jm * 16 + l16;
                const int nn = wn + qg * 16 + quad * 4;
                const float bi = bias[m0 + mm];
                bf16x4 o;
                #pragma unroll
                for (int r = 0; r < 4; r++) o[r] = (__bf16)(acc[qg][jm][r] + bi);
                *(bf16x4*)(&sm.Tv[mm][nn]) = o;
            }
        __syncthreads();
        #pragma unroll
        for (int i = 0; i < 4; i++) {
            const int mrow = i * 32 + (tid >> 3);
            const int ch = (tid & 7) * 8;
            *(bf16x8*)(Vo + (size_t)(b * C_ + m0 + mrow) * N_ + n0 + ch) =
                *(const bf16x8*)(&sm.Tv[mrow][ch]);
        }
    } else {                                      // Q/K: bf16 [bh][n][d]
        __bf16* OUTb = (sel == 0) ? Qo : Ko;
        __syncthreads();
        #pragma unroll
        for (int qg = 0; qg < 2; qg++)
            #pragma unroll
            for (int jm = 0; jm < 4; jm++) {
                const int m = m0 + wm + jm * 16 + l16;
                const float bi = bias[m];
                #pragma unroll
                for (int r = 0; r < 4; r++)
                    sm.T1[wn + qg * 16 + quad * 4 + r][wm + jm * 16 + l16] =
                        (__bf16)((acc[qg][jm][r] + bi) * psc);
            }
        __syncthreads();
        const int h0 = m0 >> 6;
        #pragma unroll
        for (int i = 0; i < 4; i++) {
            const int idx = i * 256 + tid;
            const int row = idx >> 4;
            const int c = (idx & 15) * 8;
            const int hh = h0 + (c >> 6);
            const int d = c & 63;
            *(bf16x8*)(OUTb + ((size_t)(b * NH_ + hh) * N_ + n0 + row) * HD_ + d) =
                *(const bf16x8*)(&sm.T1[row][c]);
        }
    }
}

// ---------------- final GEMM (Wo + residual): coalesced epilogue -----------------
__global__ __launch_bounds__(256, 2) void gemm_kernel(const __bf16* __restrict__ Wb,
                                                      const float* __restrict__ bias,
                                                      const __bf16* __restrict__ XT,
                                                      float* __restrict__ OUTf,
                                                      const float* __restrict__ RES) {
    const int n0 = blockIdx.x * 64;
    const int m0 = blockIdx.y * 128;
    const int b  = blockIdx.z;
    const int tid = threadIdx.x;
    const int w = tid >> 6, lane = tid & 63, quad = lane >> 4, l16 = lane & 15;
    const int wn = (w >> 1) * 32;
    const int wm = (w & 1) * 64;

    __shared__ union {
        __bf16 Wl[128][264];
        float  Tf[128][68];
    } sm;

    const __bf16* wsrc = Wb + (size_t)m0 * C_;
    #pragma unroll
    for (int i = 0; i < 16; i++) {
        const int e = i * 256 + tid;
        const int row = e >> 5;
        const int c8 = (e & 31) * 8;
        *(bf16x8*)(&sm.Wl[row][c8]) = *(const bf16x8*)(wsrc + (size_t)row * C_ + c8);
    }

    const __bf16* ap0 = XT + ((size_t)b * N_ + n0 + wn + l16) * C_ + quad * 8;
    const __bf16* ap1 = ap0 + (size_t)16 * C_;
    bf16x8 areg[2][8];
    #pragma unroll
    for (int ks = 0; ks < 8; ks++) {
        areg[0][ks] = *(const bf16x8*)(ap0 + ks * 32);
        areg[1][ks] = *(const bf16x8*)(ap1 + ks * 32);
    }

    f32x4 acc[2][4];
    #pragma unroll
    for (int qg = 0; qg < 2; qg++)
        #pragma unroll
        for (int jm = 0; jm < 4; jm++) acc[qg][jm] = (f32x4){0.f, 0.f, 0.f, 0.f};

    __syncthreads();

    #pragma unroll
    for (int ks = 0; ks < 8; ks++) {
        const int kc = ks * 32;
        #pragma unroll
        for (int jm = 0; jm < 4; jm++) {
            bf16x8 bw = *(const bf16x8*)(&sm.Wl[wm + jm * 16 + l16][kc + quad * 8]);
            acc[0][jm] = __builtin_amdgcn_mfma_f32_16x16x32_bf16(areg[0][ks], bw, acc[0][jm], 0, 0, 0);
            acc[1][jm] = __builtin_amdgcn_mfma_f32_16x16x32_bf16(areg[1][ks], bw, acc[1][jm], 0, 0, 0);
        }
    }

    __syncthreads();
    #pragma unroll
    for (int qg = 0; qg < 2; qg++)
        #pragma unroll
        for (int jm = 0; jm < 4; jm++) {
            const int mm = wm + jm * 16 + l16;
            const int nn = wn + qg * 16 + quad * 4;
            const float bi = bias[m0 + mm];
            f32x4 o;
            #pragma unroll
            for (int r = 0; r < 4; r++) o[r] = acc[qg][jm][r] + bi;
            *(f32x4*)(&sm.Tf[mm][nn]) = o;
        }
    __syncthreads();
    #pragma unroll
    for (int qp = 0; qp < 8; qp++) {
        const int mrow = qp * 16 + (tid >> 4);
        const int k4 = (tid & 15) * 4;
        const size_t off = (size_t)(b * C_ + m0 + mrow) * N_ + n0 + k4;
        const float4 res = *(const float4*)(RES + off);
        f32x4 v = *(const f32x4*)(&sm.Tf[mrow][k4]);
        v[0] += res.x; v[1] += res.y; v[2] += res.z; v[3] += res.w;
        *(f32x4*)(OUTf + off) = v;
    }
}

// ---------------- Flash attention v8 (unchanged control) -------------------------
__global__ __launch_bounds__(256, 2) void attn_kernel(const __bf16* __restrict__ qT,  // [16][N][64], scale*log2e folded
                                                      const __bf16* __restrict__ kT,  // [16][N][64]
                                                      const __bf16* __restrict__ V,   // [4][256][N]
                                                      __bf16* __restrict__ O) {       // [4][N][256]
    const int flat = blockIdx.y * 32 + blockIdx.x;
    const int bh = flat & 15;
    const int qt = flat >> 4;
    const int q0 = qt * 128;
    const int b = bh >> 2, h = bh & 3;
    const int tid = threadIdx.x;
    const int w = tid >> 6, lane = tid & 63, quad = lane >> 4, l16 = lane & 15;

    __shared__ union SMem {
        struct { __bf16 K[2][64][72]; __bf16 Vt[2][64][72]; } kv;
        __bf16 Ot[128][72];
    } sm;

    const __bf16* qTb = qT + (size_t)bh * N_ * HD_;
    const __bf16* kTb = kT + (size_t)bh * N_ * HD_;
    const __bf16* Vb  = V + ((size_t)b * C_ + h * HD_) * N_;

    bf16x8 qa[2][2];
    #pragma unroll
    for (int qg = 0; qg < 2; qg++)
        #pragma unroll
        for (int kk = 0; kk < 2; kk++)
            qa[qg][kk] = *(const bf16x8*)(qTb + (size_t)(q0 + w * 32 + qg * 16 + l16) * HD_ + kk * 32 + quad * 8);

    f32x4 oacc[2][4];
    #pragma unroll
    for (int qg = 0; qg < 2; qg++)
        #pragma unroll
        for (int j = 0; j < 4; j++) oacc[qg][j] = (f32x4){0.f, 0.f, 0.f, 0.f};
    float lsum[2] = {0.f, 0.f};

    const int srow = tid >> 3;
    const int scol = (tid & 7) * 8;

    bf16x8 rk[2], rv[2];
    #pragma unroll
    for (int i = 0; i < 2; i++) {
        const int row = srow + i * 32;
        rk[i] = *(const bf16x8*)(kTb + (size_t)row * HD_ + scol);
        rv[i] = *(const bf16x8*)(Vb + (size_t)row * N_ + scol);
    }

    for (int it = 0; it < N_ / 64; it++) {
        const int cur = it & 1;
        const int nm0 = ((it + 1) * 64) & (N_ - 1);
        #pragma unroll
        for (int i = 0; i < 2; i++) {
            const int row = srow + i * 32;
            *(bf16x8*)(&sm.kv.K[cur][row][scol])  = rk[i];
            *(bf16x8*)(&sm.kv.Vt[cur][row][scol]) = rv[i];
        }
        #pragma unroll
        for (int i = 0; i < 2; i++) {
            const int row = srow + i * 32;
            rk[i] = *(const bf16x8*)(kTb + (size_t)(nm0 + row) * HD_ + scol);
            rv[i] = *(const bf16x8*)(Vb + (size_t)row * N_ + nm0 + scol);
        }
        asm volatile("s_waitcnt lgkmcnt(0)" ::: "memory");
        __builtin_amdgcn_s_barrier();
        bf16x8 kb[2][4], vb[2][4];
        #pragma unroll
        for (int kk = 0; kk < 2; kk++)
            #pragma unroll
            for (int j = 0; j < 4; j++) {
                kb[kk][j] = *(const bf16x8*)(&sm.kv.K[cur][j * 16 + l16][kk * 32 + quad * 8]);
                vb[kk][j] = *(const bf16x8*)(&sm.kv.Vt[cur][j * 16 + l16][kk * 32 + quad * 8]);
            }
        #pragma unroll
        for (int qg = 0; qg < 2; qg++) {
            f32x4 s[4];
            #pragma unroll
            for (int j = 0; j < 4; j++) s[j] = (f32x4){0.f, 0.f, 0.f, 0.f};
            #pragma unroll
            for (int kk = 0; kk < 2; kk++)
                #pragma unroll
                for (int j = 0; j < 4; j++)
                    s[j] = __builtin_amdgcn_mfma_f32_16x16x32_bf16(kb[kk][j], qa[qg][kk], s[j], 0, 0, 0);
            float p[4][4];
            float ls = 0.f;
            #pragma unroll
            for (int j = 0; j < 4; j++) {
                #pragma unroll
                for (int r = 0; r < 4; r++) p[j][r] = EXP2F(s[j][r]);
                ls += (p[j][0] + p[j][1]) + (p[j][2] + p[j][3]);
            }
            lsum[qg] += ls;
            unsigned int pk0[4], pk1[4];
            #pragma unroll
            for (int j = 0; j < 4; j++) {
                pk0[j] = packbf(p[j][0], p[j][1]);
                pk1[j] = packbf(p[j][2], p[j][3]);
            }
            #pragma unroll
            for (int kk = 0; kk < 2; kk++) {
                u32x2 t0 = __builtin_amdgcn_permlane32_swap(pk0[2 * kk], pk0[2 * kk + 1], false, false);
                u32x2 t1 = __builtin_amdgcn_permlane32_swap(pk1[2 * kk], pk1[2 * kk + 1], false, false);
                u32x2 a0 = __builtin_amdgcn_permlane16_swap(t0[0], t0[1], false, false);
                u32x2 a1 = __builtin_amdgcn_permlane16_swap(t1[0], t1[1], false, false);
                bf16x8 pb = __builtin_bit_cast(bf16x8, (u32x4){a0[0], a1[0], a0[1], a1[1]});
                #pragma unroll
                for (int jd = 0; jd < 4; jd++)
                    oacc[qg][jd] = __builtin_amdgcn_mfma_f32_16x16x32_bf16(vb[kk][jd], pb, oacc[qg][jd], 0, 0, 0);
            }
        }
    }
    float inv[2];
    #pragma unroll
    for (int qg = 0; qg < 2; qg++) {
        float l = lsum[qg];
        l += __shfl_xor(l, 16);
        l += __shfl_xor(l, 32);
        inv[qg] = 1.f / l;
    }
    __syncthreads();
    #pragma unroll
    for (int qg = 0; qg < 2; qg++) {
        #pragma unroll
        for (int jd = 0; jd < 4; jd++) {
            bf16x4 o;
            #pragma unroll
            for (int r = 0; r < 4; r++) o[r] = (__bf16)(oacc[qg][jd][r] * inv[qg]);
            *(bf16x4*)(&sm.Ot[w * 32 + qg * 16 + l16][jd * 16 + quad * 4]) = o;
        }
    }
    __syncthreads();
    __bf16* Ob = O + ((size_t)b * N_ + q0) * C_ + h * HD_;
    const int row0 = tid >> 3, chh = (tid & 7) * 8;
    #pragma unroll
    for (int i = 0; i < 4; i++) {
        const int row = row0 + i * 32;
        *(bf16x8*)(Ob + (size_t)row * C_ + chh) = *(const bf16x8*)(&sm.Ot[row][chh]);
    }
}

extern "C" void kernel_launch(void* const* d_in, const int* in_sizes, int n_in,
                              void* d_out, int out_size, void* d_ws, size_t ws_size,
                              hipStream_t stream) {
    const float* x     = (const float*)d_in[0];
    const float* cond  = (const float*)d_in[1];
    const float* gnqw  = (const float*)d_in[2];
    const float* gnqb  = (const float*)d_in[3];
    const float* gnkw  = (const float*)d_in[4];
    const float* gnkb  = (const float*)d_in[5];
    const float* wq    = (const float*)d_in[6];
    const float* bq    = (const float*)d_in[7];
    const float* wk    = (const float*)d_in[8];
    const float* bk    = (const float*)d_in[9];
    const float* wv    = (const float*)d_in[10];
    const float* bv    = (const float*)d_in[11];
    const float* wo    = (const float*)d_in[12];
    const float* bo    = (const float*)d_in[13];
    float* out = (float*)d_out;

    const size_t TEN = (size_t)B_ * C_ * N_;
    const size_t WSZ = (size_t)C_ * C_;
    __bf16* gnx   = (__bf16*)d_ws;      // [b][n][c]
    __bf16* gnc   = gnx + TEN;          // [b][n][c]
    __bf16* qT    = gnc + TEN;          // [bh][n][d]
    __bf16* kT    = qT  + TEN;          // [bh][n][d]
    __bf16* v     = kT  + TEN;          // [b][c][n]
    __bf16* attno = v   + TEN;          // [b][n][c]
    __bf16* wb    = attno + TEN;        // 4x [256][256] bf16 (q,k,v,o)
    float*  stat  = (float*)(wb + 4 * WSZ);   // [2][2][B][C] f32 (sc/sh per input)

    wconv_kernel<<<dim3(64, 4), 256, 0, stream>>>(wq, wk, wv, wo, wb);

    gn_stats_kernel<<<dim3(B_ * G_, 2), 1024, 0, stream>>>(x, cond, gnqw, gnqb, gnkw, gnkb, stat);
    gn_norm_kernel<<<dim3(N_ / 64, B_, 2), 256, 0, stream>>>(x, cond, stat, gnx, gnc);

    qkv_kernel<<<dim3(N_ / 64, 6, B_), 256, 0, stream>>>(wb, bq, bk, bv, gnx, gnc,
                                                         qT, kT, v,
                                                         0.125f * 1.44269504088896f);

    attn_kernel<<<dim3(32, 16), 256, 0, stream>>>(qT, kT, v, attno);

    gemm_kernel<<<dim3(N_ / 64, C_ / 128, B_), 256, 0, stream>>>(wb + 3 * WSZ, bo, attno, out, x);
}